// Round 13
// baseline (180.672 us; speedup 1.0000x reference)
//
#include <hip/hip_runtime.h>
#include <hip/hip_bf16.h>

#define D768 768

typedef __attribute__((ext_vector_type(8))) short short8;
typedef __attribute__((ext_vector_type(4))) float f32x4;

__device__ __forceinline__ unsigned short f2bf(float f){
  union { float f; unsigned u; } v; v.f = f;
  unsigned r = v.u + 0x7FFFu + ((v.u >> 16) & 1u);
  return (unsigned short)(r >> 16);
}
__device__ __forceinline__ float bf2f(unsigned short u){
  union { unsigned u; float f; } v; v.u = ((unsigned)u) << 16;
  return v.f;
}
// exact-erf GELU via Abramowitz-Stegun 7.1.26 (|eps| <= 1.5e-7), ~13 VALU + exp + rcp
__device__ __forceinline__ float gelu_f(float x){
  float y = fabsf(x) * 0.7071067811865475f;
  float t = __builtin_amdgcn_rcpf(fmaf(0.3275911f, y, 1.0f));
  float p = fmaf(fmaf(fmaf(fmaf(1.061405429f, t, -1.453152027f), t, 1.421413741f),
                      t, -0.284496736f), t, 0.254829592f) * t;
  float e = __expf(-y * y);
  float erf_abs = fmaf(-p, e, 1.0f);
  float erfv = copysignf(erf_abs, x);
  return 0.5f * x * (1.0f + erfv);
}
__device__ __forceinline__ void gload16(const void* g, void* l){
  __builtin_amdgcn_global_load_lds((const __attribute__((address_space(1))) void*)g,
                                   (__attribute__((address_space(3))) void*)l, 16, 0, 0);
}

// ---------- LayerNorm over rows of 768; optional f32 out + bf16 out ----------
__global__ void k_ln(const float* __restrict__ x, const float* __restrict__ g,
                     const float* __restrict__ bia, float* __restrict__ of32,
                     unsigned short* __restrict__ obf, int ldo){
  int row = blockIdx.x;
  int t = threadIdx.x; // 192 threads, 4 floats each
  const float* xr = x + (size_t)row * D768;
  float4 v = *(const float4*)(xr + t*4);
  float s  = v.x + v.y + v.z + v.w;
  float ss = v.x*v.x + v.y*v.y + v.z*v.z + v.w*v.w;
  for (int o = 32; o; o >>= 1){ s += __shfl_down(s, o); ss += __shfl_down(ss, o); }
  __shared__ float sb[6];
  int wid = t >> 6;
  if ((t & 63) == 0){ sb[wid] = s; sb[3+wid] = ss; }
  __syncthreads();
  s = sb[0] + sb[1] + sb[2]; ss = sb[3] + sb[4] + sb[5];
  float mean = s * (1.f/768.f);
  float var  = ss * (1.f/768.f) - mean*mean;
  float rstd = rsqrtf(var + 1e-5f);
  float4 gv = *(const float4*)(g + t*4);
  float4 bv = *(const float4*)(bia + t*4);
  float o0 = (v.x-mean)*rstd*gv.x + bv.x;
  float o1 = (v.y-mean)*rstd*gv.y + bv.y;
  float o2 = (v.z-mean)*rstd*gv.z + bv.z;
  float o3 = (v.w-mean)*rstd*gv.w + bv.w;
  if (of32){
    float4 ov; ov.x=o0; ov.y=o1; ov.z=o2; ov.w=o3;
    *(float4*)(of32 + (size_t)row * D768 + t*4) = ov;
  }
  ushort4 ub; ub.x=f2bf(o0); ub.y=f2bf(o1); ub.z=f2bf(o2); ub.w=f2bf(o3);
  *(ushort4*)(obf + (size_t)row * ldo + t*4) = ub;
}

// ---------- init (blocks 0..127) + tiled transpose+cast of weights (blocks 128..) ----------
__global__ void k_wtall(const float* __restrict__ sw1, const float* __restrict__ gw1,
                        unsigned short* __restrict__ WtA, unsigned short* __restrict__ WtB,
                        unsigned short* __restrict__ WtG,
                        float* __restrict__ scores, const float* __restrict__ sb2,
                        float* __restrict__ gacc, const float* __restrict__ gb2,
                        const unsigned char* __restrict__ m, int* __restrict__ flag){
  int blk = blockIdx.x;
  if (blk < 128){
    int i = blk * 256 + threadIdx.x;
    if (i < 32768) scores[i] = sb2[0];
    if (i < 4096)  gacc[i]   = gb2[0];
    if (blk == 0){
      __shared__ int s;
      if (threadIdx.x == 0) s = 0;
      __syncthreads();
      int nz = 0;
      for (int j = threadIdx.x; j < 2048; j += 256) nz += (m[4*j+1] != 0);
      atomicAdd(&s, nz);
      __syncthreads();
      if (threadIdx.x == 0) *flag = (s == 0) ? 1 : 0; // 1 => 4-byte mask elems
    }
    return;
  }
  int tile = blk - 128;
  const float* W; unsigned short* Wt; int Kin, Kpad;
  if (tile < 576)      { W = sw1;                 Wt = WtA; Kin = 768;  Kpad = 768;  }
  else if (tile < 1152){ W = sw1 + 768ull*768;    Wt = WtB; Kin = 768;  Kpad = 768;  tile -= 576; }
  else                 { W = gw1;                 Wt = WtG; Kin = 1552; Kpad = 1568; tile -= 1152; }
  int ntk = Kpad >> 5;
  int k0 = (tile % ntk) << 5, n0 = (tile / ntk) << 5;
  __shared__ float ts[32][33];
  int tx = threadIdx.x & 31, ty = threadIdx.x >> 5; // 32x8
  #pragma unroll
  for (int r = 0; r < 4; ++r){
    int k = k0 + ty + r*8;
    ts[ty + r*8][tx] = (k < Kin) ? W[(size_t)k * D768 + n0 + tx] : 0.f;
  }
  __syncthreads();
  #pragma unroll
  for (int r = 0; r < 4; ++r){
    int n = n0 + ty + r*8;
    Wt[(size_t)n * Kpad + k0 + tx] = f2bf(ts[tx][ty + r*8]);
  }
}

// ---------- 4-wave MFMA GEMM (tproj / gate), 128xBN tile, depth-3 ring ----------
// ONE barrier per K-step (WAR-safe), counted vmcnt, both-sides segment swizzle,
// XCD-aware block swizzle. MODE 0: store C fp32.  MODE 2: gate epilogue.
template<int MODE, int BN>
__launch_bounds__(256)
__global__ void k_gemm(const unsigned short* __restrict__ A, int lda,
                       const unsigned short* __restrict__ Bt, int ldb,
                       int ksteps, int ntn,
                       const float* __restrict__ tproj,
                       const float* __restrict__ b1,
                       const float* __restrict__ w2,
                       float* __restrict__ out){
  constexpr int NJ  = BN / 32;  // n-frags per wave
  constexpr int BCH = BN / 64;  // B chunks per wave per stage
  __shared__ __align__(16) unsigned short As[3][128*32];
  __shared__ __align__(16) unsigned short Bs[3][BN*32];
  const int cpx = gridDim.x >> 3;
  const int logical = ((int)blockIdx.x & 7) * cpx + ((int)blockIdx.x >> 3);
  const int m0 = (logical / ntn) * 128, n0 = (logical % ntn) * BN;
  const int t = threadIdx.x, lane = t & 63, w = t >> 6;
  const int wrow = (w >> 1) * 64, wcol = (w & 1) * (BN/2);
  const int lo16 = lane & 15;
  const int hs = ((lane >> 4) ^ ((lo16 >> 1) & 3)) * 8;
  const int crow = lane >> 2;
  const int cseg = (((lane & 3) ^ ((lane >> 3) & 3)) * 8);
  const unsigned short* ga = A  + (size_t)(m0 + w*32 + crow) * lda + cseg;
  const unsigned short* gb = Bt + (size_t)(n0 + w*(BN/4) + crow) * ldb + cseg;
  f32x4 acc[4][NJ] = {};

#define STAGEK(BUF, KS) do {                                                   \
    const unsigned short* gak_ = ga + (size_t)(KS)*32;                         \
    const unsigned short* gbk_ = gb + (size_t)(KS)*32;                         \
    _Pragma("unroll")                                                          \
    for (int c = 0; c < 2; ++c)                                                \
      gload16(gak_ + (size_t)(c*16)*lda, &As[BUF][w*1024 + c*512]);            \
    _Pragma("unroll")                                                          \
    for (int c = 0; c < BCH; ++c)                                              \
      gload16(gbk_ + (size_t)(c*16)*ldb, &Bs[BUF][w*(BN/4)*32 + c*512]);       \
  } while (0)

#define COMPUTEK(BUF) do {                                                     \
    const unsigned short* pa_ = &As[BUF][(wrow + lo16)*32 + hs];               \
    const unsigned short* pb_ = &Bs[BUF][(wcol + lo16)*32 + hs];               \
    short8 af_[4], bf_[NJ];                                                    \
    _Pragma("unroll")                                                          \
    for (int i = 0; i < 4; ++i) af_[i] = *(const short8*)(pa_ + i*16*32);      \
    _Pragma("unroll")                                                          \
    for (int j = 0; j < NJ; ++j) bf_[j] = *(const short8*)(pb_ + j*16*32);     \
    _Pragma("unroll")                                                          \
    for (int i = 0; i < 4; ++i)                                                \
      _Pragma("unroll")                                                        \
      for (int j = 0; j < NJ; ++j)                                             \
        acc[i][j] = __builtin_amdgcn_mfma_f32_16x16x32_bf16(af_[i], bf_[j], acc[i][j], 0, 0, 0); \
  } while (0)

#define WAITN(n) asm volatile("s_waitcnt vmcnt(" #n ")" ::: "memory")

  {
    int pro = ksteps < 2 ? ksteps : 2;
    for (int p = 0; p < pro; ++p) STAGEK(p, p);
  }
  for (int ks = 0; ks < ksteps; ++ks){
    int rem = ksteps - ks;
    if (rem >= 2){ if constexpr (BCH == 2) WAITN(4); else WAITN(3); }
    else WAITN(0);
    __builtin_amdgcn_s_barrier();
    __builtin_amdgcn_sched_barrier(0);
    if (ks + 2 < ksteps) STAGEK((ks + 2) % 3, ks + 2);
    COMPUTEK(ks % 3);
  }
#undef STAGEK
#undef COMPUTEK
#undef WAITN

  if (MODE == 0){
    #pragma unroll
    for (int i = 0; i < 4; ++i)
      #pragma unroll
      for (int reg = 0; reg < 4; ++reg){
        int row = m0 + wrow + i*16 + ((lane >> 4) << 2) + reg;
        float* orow = out + (size_t)row * D768 + n0 + wcol + (lane & 15);
        #pragma unroll
        for (int j = 0; j < NJ; ++j) orow[j*16] = acc[i][j][reg];
      }
  } else {
    #pragma unroll
    for (int i = 0; i < 4; ++i)
      #pragma unroll
      for (int reg = 0; reg < 4; ++reg){
        int row = m0 + wrow + i*16 + ((lane >> 4) << 2) + reg;
        const float* tp = nullptr;
        if (MODE == 1){
          int trow = ((row >> 13) << 10) | (row & 1023);
          tp = tproj + (size_t)trow * D768;
        }
        float contrib = 0.f;
        #pragma unroll
        for (int j = 0; j < NJ; ++j){
          int n = n0 + wcol + j*16 + (lane & 15);
          float v = acc[i][j][reg] + b1[n];
          if (MODE == 1) v += tp[n];
          contrib += gelu_f(v) * w2[n];
        }
        for (int o = 8; o; o >>= 1) contrib += __shfl_xor(contrib, o);
        if ((lane & 15) == 0) atomicAdd(&out[row], contrib);
      }
  }
}

// ---------- 8-wave MFMA GEMM (score), 128x128 tile, depth-3 ring ----------
// 512 threads, wave grid 2M x 4N (each wave 64x32, NJ=2). Same LDS (48KB) but
// 8 waves/block -> 3 blocks/CU = 24 waves = 75% occupancy (vs 37.5% at 4-wave):
// doubles the TLP that fills vmcnt/barrier stall holes (m114 overlap model).
// Stage: 1 A-chunk + 1 B-chunk (16 rows) per wave; L=2 -> steady vmcnt(2).
// Ring/barrier/WAR proofs and both-sides swizzle identical to 4-wave version.
__launch_bounds__(512)
__global__ void k_gemm8(const unsigned short* __restrict__ A, int lda,
                        const unsigned short* __restrict__ Bt, int ldb,
                        int ksteps, int ntn,
                        const float* __restrict__ tproj,
                        const float* __restrict__ b1,
                        const float* __restrict__ w2,
                        float* __restrict__ out){
  __shared__ __align__(16) unsigned short As[3][128*32];
  __shared__ __align__(16) unsigned short Bs[3][128*32];
  const int cpx = gridDim.x >> 3;
  const int logical = ((int)blockIdx.x & 7) * cpx + ((int)blockIdx.x >> 3);
  const int m0 = (logical / ntn) * 128, n0 = (logical % ntn) * 128;
  const int t = threadIdx.x, lane = t & 63, w = t >> 6; // 8 waves
  const int wrow = (w >> 2) * 64, wcol = (w & 3) * 32;
  const int lo16 = lane & 15;
  const int hs = ((lane >> 4) ^ ((lo16 >> 1) & 3)) * 8;
  const int crow = lane >> 2;
  const int cseg = (((lane & 3) ^ ((lane >> 3) & 3)) * 8);
  const unsigned short* ga = A  + (size_t)(m0 + w*16 + crow) * lda + cseg;
  const unsigned short* gb = Bt + (size_t)(n0 + w*16 + crow) * ldb + cseg;
  f32x4 acc[4][2] = {};

#define STAGEK(BUF, KS) do {                                                   \
    gload16(ga + (size_t)(KS)*32, &As[BUF][w*512]);                            \
    gload16(gb + (size_t)(KS)*32, &Bs[BUF][w*512]);                            \
  } while (0)

#define COMPUTEK(BUF) do {                                                     \
    const unsigned short* pa_ = &As[BUF][(wrow + lo16)*32 + hs];               \
    const unsigned short* pb_ = &Bs[BUF][(wcol + lo16)*32 + hs];               \
    short8 af_[4], bf_[2];                                                     \
    _Pragma("unroll")                                                          \
    for (int i = 0; i < 4; ++i) af_[i] = *(const short8*)(pa_ + i*16*32);      \
    _Pragma("unroll")                                                          \
    for (int j = 0; j < 2; ++j) bf_[j] = *(const short8*)(pb_ + j*16*32);      \
    _Pragma("unroll")                                                          \
    for (int i = 0; i < 4; ++i)                                                \
      _Pragma("unroll")                                                        \
      for (int j = 0; j < 2; ++j)                                              \
        acc[i][j] = __builtin_amdgcn_mfma_f32_16x16x32_bf16(af_[i], bf_[j], acc[i][j], 0, 0, 0); \
  } while (0)

#define WAITN(n) asm volatile("s_waitcnt vmcnt(" #n ")" ::: "memory")

  {
    int pro = ksteps < 2 ? ksteps : 2;
    for (int p = 0; p < pro; ++p) STAGEK(p, p);
  }
  for (int ks = 0; ks < ksteps; ++ks){
    int rem = ksteps - ks;
    if (rem >= 2) WAITN(2);
    else WAITN(0);
    __builtin_amdgcn_s_barrier();
    __builtin_amdgcn_sched_barrier(0);
    if (ks + 2 < ksteps) STAGEK((ks + 2) % 3, ks + 2);
    COMPUTEK(ks % 3);
  }
#undef STAGEK
#undef COMPUTEK
#undef WAITN

  // score epilogue: +tproj+b1, gelu, *w2, partial rowsum over this wave's 32 cols,
  // 16-lane shuffle reduce, atomicAdd (4 waves + 6 blocks accumulate per row)
  #pragma unroll
  for (int i = 0; i < 4; ++i)
    #pragma unroll
    for (int reg = 0; reg < 4; ++reg){
      int row = m0 + wrow + i*16 + ((lane >> 4) << 2) + reg;
      int trow = ((row >> 13) << 10) | (row & 1023); // (b*8+s)*1024+t -> b*1024+t
      const float* tp = tproj + (size_t)trow * D768;
      float contrib = 0.f;
      #pragma unroll
      for (int j = 0; j < 2; ++j){
        int n = n0 + wcol + j*16 + lo16;
        float v = acc[i][j][reg] + b1[n] + tp[n];
        contrib += gelu_f(v) * w2[n];
      }
      for (int o = 8; o; o >>= 1) contrib += __shfl_xor(contrib, o);
      if (lo16 == 0) atomicAdd(&out[row], contrib);
    }
}

// ---------- masked softmax over S=8 + weighted summary -> gcat[:,768:1568] (bf16) ----------
__global__ void k_smx(const float* __restrict__ scores, const void* __restrict__ maskp,
                      const int* __restrict__ flag, const unsigned short* __restrict__ sh,
                      const float* __restrict__ feat,
                      unsigned short* __restrict__ gcat){
  int bt = blockIdx.x;
  int b = bt >> 10, tt = bt & 1023;
  int t = threadIdx.x; // 192
  int f = *flag;
  float sc[8], mk[8];
  #pragma unroll
  for (int s = 0; s < 8; ++s){
    size_t idx = ((size_t)(b*8 + s) << 10) + tt;
    bool m = f ? (((const int*)maskp)[idx] != 0)
               : (((const unsigned char*)maskp)[idx] != 0);
    mk[s] = m ? 1.f : 0.f;
    float v = scores[idx];
    sc[s] = m ? v : -10000.f;
  }
  float mx = sc[0];
  #pragma unroll
  for (int s = 1; s < 8; ++s) mx = fmaxf(mx, sc[s]);
  float e[8], sum = 0.f;
  #pragma unroll
  for (int s = 0; s < 8; ++s){ e[s] = __expf(sc[s] - mx); sum += e[s]; }
  float inv = 1.f / sum;
  float wv[8], sum2 = 0.f;
  #pragma unroll
  for (int s = 0; s < 8; ++s){ wv[s] = e[s] * inv * mk[s]; sum2 += wv[s]; }
  float inv2 = 1.f / fmaxf(sum2, 1e-8f);
  #pragma unroll
  for (int s = 0; s < 8; ++s) wv[s] *= inv2;
  float a0=0.f, a1=0.f, a2=0.f, a3=0.f;
  #pragma unroll
  for (int s = 0; s < 8; ++s){
    const unsigned short* p = sh + (((size_t)(b*8+s) << 10) + tt) * D768 + t*4;
    ushort4 u = *(const ushort4*)p;
    float ws = wv[s];
    a0 += ws * bf2f(u.x); a1 += ws * bf2f(u.y); a2 += ws * bf2f(u.z); a3 += ws * bf2f(u.w);
  }
  ushort4 ub; ub.x=f2bf(a0); ub.y=f2bf(a1); ub.z=f2bf(a2); ub.w=f2bf(a3);
  *(ushort4*)(gcat + (size_t)bt * 1568 + 768 + t*4) = ub;
  if (t < 8){
    int c = 1536 + t*4;
    float4 fv = make_float4(0.f, 0.f, 0.f, 0.f);
    if (c < 1552) fv = *(const float4*)(feat + (size_t)bt * 16 + (c - 1536));
    ushort4 uf; uf.x=f2bf(fv.x); uf.y=f2bf(fv.y); uf.z=f2bf(fv.z); uf.w=f2bf(fv.w);
    *(ushort4*)(gcat + (size_t)bt * 1568 + c) = uf;
  }
}

// ---------- gate=sigmoid(gacc); x=(2-g)*th+g*summary(bf16 from gcat); out=LN(x) ----------
__global__ void k_final(const float* __restrict__ th, const unsigned short* __restrict__ gcat,
                        const float* __restrict__ gacc, const float* __restrict__ og,
                        const float* __restrict__ ob, float* __restrict__ out,
                        float* __restrict__ outg){
  int r = blockIdx.x, t = threadIdx.x; // 192
  float gv = 1.f / (1.f + __expf(-gacc[r]));
  if (t == 0) outg[r] = gv;
  float4 tv = *(const float4*)(th + (size_t)r * D768 + t*4);
  ushort4 su = *(const ushort4*)(gcat + (size_t)r * 1568 + 768 + t*4);
  float s0 = bf2f(su.x), s1 = bf2f(su.y), s2 = bf2f(su.z), s3 = bf2f(su.w);
  float x0 = (2.f-gv)*tv.x + gv*s0;
  float x1 = (2.f-gv)*tv.y + gv*s1;
  float x2 = (2.f-gv)*tv.z + gv*s2;
  float x3 = (2.f-gv)*tv.w + gv*s3;
  float s = x0+x1+x2+x3, ss = x0*x0+x1*x1+x2*x2+x3*x3;
  for (int o = 32; o; o >>= 1){ s += __shfl_down(s,o); ss += __shfl_down(ss,o); }
  __shared__ float sb[6];
  int wid = t >> 6;
  if ((t&63)==0){ sb[wid]=s; sb[3+wid]=ss; }
  __syncthreads();
  s = sb[0]+sb[1]+sb[2]; ss = sb[3]+sb[4]+sb[5];
  float mean = s*(1.f/768.f), var = ss*(1.f/768.f)-mean*mean;
  float rstd = rsqrtf(var + 1e-5f);
  float4 gvv = *(const float4*)(og + t*4);
  float4 bvv = *(const float4*)(ob + t*4);
  float4 ov;
  ov.x = (x0-mean)*rstd*gvv.x + bvv.x;
  ov.y = (x1-mean)*rstd*gvv.y + bvv.y;
  ov.z = (x2-mean)*rstd*gvv.z + bvv.z;
  ov.w = (x3-mean)*rstd*gvv.w + bvv.w;
  *(float4*)(out + (size_t)r * D768 + t*4) = ov;
}

extern "C" void kernel_launch(void* const* d_in, const int* in_sizes, int n_in,
                              void* d_out, int out_size, void* d_ws, size_t ws_size,
                              hipStream_t stream){
  const float* target = (const float*)d_in[0];
  const float* support= (const float*)d_in[1];
  const void*  maskp  = d_in[2];
  const float* feat   = (const float*)d_in[3];
  const float* t_g = (const float*)d_in[4];
  const float* t_b = (const float*)d_in[5];
  const float* s_g = (const float*)d_in[6];
  const float* s_b = (const float*)d_in[7];
  const float* o_g = (const float*)d_in[8];
  const float* o_b = (const float*)d_in[9];
  const float* sw1 = (const float*)d_in[10];
  const float* sb1 = (const float*)d_in[11];
  const float* sw2 = (const float*)d_in[12];
  const float* sb2 = (const float*)d_in[13];
  const float* gw1 = (const float*)d_in[14];
  const float* gb1 = (const float*)d_in[15];
  const float* gw2 = (const float*)d_in[16];
  const float* gb2 = (const float*)d_in[17];

  char* wsb = (char*)d_ws;
  size_t off = 0;
  auto alloc = [&](size_t bytes)->void*{
    void* p = wsb + off; off += (bytes + 255) & ~(size_t)255; return p;
  };
  float* th            = (float*)alloc(4096ull*768*4);
  unsigned short* sh   = (unsigned short*)alloc(32768ull*768*2);
  float* tproj         = (float*)alloc(4096ull*768*4);
  unsigned short* gcat = (unsigned short*)alloc(4096ull*1568*2);
  unsigned short* WtA  = (unsigned short*)alloc(768ull*768*2);
  unsigned short* WtB  = (unsigned short*)alloc(768ull*768*2);
  unsigned short* WtG  = (unsigned short*)alloc(768ull*1568*2);
  float* scores        = (float*)alloc(32768ull*4);
  float* gacc          = (float*)alloc(4096ull*4);
  int*   flag          = (int*)alloc(256);

  float* outm = (float*)d_out;       // (B,T,D)
  float* outg = outm + 4096ull*768;  // (B,T)

  // init + maskdet + weight transposes
  k_wtall<<<2456, 256, 0, stream>>>(sw1, gw1, WtA, WtB, WtG,
                                    scores, sb2, gacc, gb2,
                                    (const unsigned char*)maskp, flag);
  // target LN -> th (f32) and gcat[:, 0:768] (bf16)
  k_ln<<<4096, 192, 0, stream>>>(target, t_g, t_b, th, gcat, 1568);
  // tproj = th @ W1a   (384 blocks 1D, ntn=12)
  k_gemm<0,64><<<384, 256, 0, stream>>>(gcat, 1568, WtA, 768, 24, 12,
                                        nullptr, nullptr, nullptr, tproj);
  // support LN -> sh (bf16)
  k_ln<<<32768, 192, 0, stream>>>(support, s_g, s_b, (float*)nullptr, sh, 768);
  // scores += rowsum(gelu(sh@W1b + tproj + b1) * w2)   (8-wave, 1536 blocks, ntn=6)
  k_gemm8<<<1536, 512, 0, stream>>>(sh, 768, WtB, 768, 24, 6,
                                    tproj, sb1, sw2, scores);
  // masked softmax + summary -> gcat[:, 768:1568]
  k_smx<<<4096, 192, 0, stream>>>(scores, maskp, flag, sh, feat, gcat);
  // gate_acc += rowsum(gelu(gcat@gW1 + gb1) * gw2)   (384 blocks 1D, ntn=12)
  k_gemm<2,64><<<384, 256, 0, stream>>>(gcat, 1568, WtG, 1568, 49, 12,
                                        nullptr, gb1, gw2, gacc);
  k_final<<<4096, 192, 0, stream>>>(th, gcat, gacc, o_g, o_b, outm, outg);
}

// Round 14
// 174.215 us; speedup vs baseline: 1.0371x; 1.0371x over previous
//
#include <hip/hip_runtime.h>
#include <hip/hip_bf16.h>

#define D768 768

typedef __attribute__((ext_vector_type(8))) short short8;
typedef __attribute__((ext_vector_type(4))) float f32x4;

__device__ __forceinline__ unsigned short f2bf(float f){
  union { float f; unsigned u; } v; v.f = f;
  unsigned r = v.u + 0x7FFFu + ((v.u >> 16) & 1u);
  return (unsigned short)(r >> 16);
}
__device__ __forceinline__ float bf2f(unsigned short u){
  union { unsigned u; float f; } v; v.u = ((unsigned)u) << 16;
  return v.f;
}
// exact-erf GELU via Abramowitz-Stegun 7.1.26 (|eps| <= 1.5e-7), ~13 VALU + exp + rcp
__device__ __forceinline__ float gelu_f(float x){
  float y = fabsf(x) * 0.7071067811865475f;
  float t = __builtin_amdgcn_rcpf(fmaf(0.3275911f, y, 1.0f));
  float p = fmaf(fmaf(fmaf(fmaf(1.061405429f, t, -1.453152027f), t, 1.421413741f),
                      t, -0.284496736f), t, 0.254829592f) * t;
  float e = __expf(-y * y);
  float erf_abs = fmaf(-p, e, 1.0f);
  float erfv = copysignf(erf_abs, x);
  return 0.5f * x * (1.0f + erfv);
}
__device__ __forceinline__ void gload16(const void* g, void* l){
  __builtin_amdgcn_global_load_lds((const __attribute__((address_space(1))) void*)g,
                                   (__attribute__((address_space(3))) void*)l, 16, 0, 0);
}

// ---------- MEGA kernel: init (0..127) + weight transpose (128..2455) +
// target LN (2456..3479, 4 rows/block) + support LN (3480..11671, 4 rows/block).
// All roles independent; merged so the BW-bound support-LN covers the others.
// LN: one wave per row, xor-butterfly reduce, no LDS/syncthreads.
__global__ __launch_bounds__(256)
void k_mega(const float* __restrict__ target, const float* __restrict__ support,
            const float* __restrict__ t_g, const float* __restrict__ t_b,
            const float* __restrict__ s_g, const float* __restrict__ s_b,
            float* __restrict__ th, unsigned short* __restrict__ gcat,
            unsigned short* __restrict__ sh,
            const float* __restrict__ sw1, const float* __restrict__ gw1,
            unsigned short* __restrict__ WtA, unsigned short* __restrict__ WtB,
            unsigned short* __restrict__ WtG,
            float* __restrict__ scores, const float* __restrict__ sb2,
            float* __restrict__ gacc, const float* __restrict__ gb2,
            const unsigned char* __restrict__ m, int* __restrict__ flag){
  int blk = blockIdx.x;
  int t = threadIdx.x;
  if (blk < 128){
    int i = blk * 256 + t;
    if (i < 32768) scores[i] = sb2[0];
    if (i < 4096)  gacc[i]   = gb2[0];
    if (blk == 0){
      __shared__ int s;
      if (t == 0) s = 0;
      __syncthreads();
      int nz = 0;
      for (int j = t; j < 2048; j += 256) nz += (m[4*j+1] != 0);
      atomicAdd(&s, nz);
      __syncthreads();
      if (t == 0) *flag = (s == 0) ? 1 : 0; // 1 => 4-byte mask elems
    }
    return;
  }
  if (blk < 2456){
    int tile = blk - 128;
    const float* W; unsigned short* Wt; int Kin, Kpad;
    if (tile < 576)      { W = sw1;              Wt = WtA; Kin = 768;  Kpad = 768;  }
    else if (tile < 1152){ W = sw1 + 768ull*768; Wt = WtB; Kin = 768;  Kpad = 768;  tile -= 576; }
    else                 { W = gw1;              Wt = WtG; Kin = 1552; Kpad = 1568; tile -= 1152; }
    int ntk = Kpad >> 5;
    int k0 = (tile % ntk) << 5, n0 = (tile / ntk) << 5;
    __shared__ float ts[32][33];
    int tx = t & 31, ty = t >> 5; // 32x8
    #pragma unroll
    for (int r = 0; r < 4; ++r){
      int k = k0 + ty + r*8;
      ts[ty + r*8][tx] = (k < Kin) ? W[(size_t)k * D768 + n0 + tx] : 0.f;
    }
    __syncthreads();
    #pragma unroll
    for (int r = 0; r < 4; ++r){
      int n = n0 + ty + r*8;
      Wt[(size_t)n * Kpad + k0 + tx] = f2bf(ts[tx][ty + r*8]);
    }
    return;
  }
  // LayerNorm: 1 wave per row, 4 rows per block
  bool isT = blk < 3480;
  int row = (isT ? (blk - 2456) : (blk - 3480)) * 4 + (t >> 6);
  int lane = t & 63;
  const float* xr = (isT ? target : support) + (size_t)row * D768;
  float4 v0 = *(const float4*)(xr + lane*4);
  float4 v1 = *(const float4*)(xr + 256 + lane*4);
  float4 v2 = *(const float4*)(xr + 512 + lane*4);
  float s  = v0.x+v0.y+v0.z+v0.w + v1.x+v1.y+v1.z+v1.w + v2.x+v2.y+v2.z+v2.w;
  float ss = v0.x*v0.x+v0.y*v0.y+v0.z*v0.z+v0.w*v0.w
           + v1.x*v1.x+v1.y*v1.y+v1.z*v1.z+v1.w*v1.w
           + v2.x*v2.x+v2.y*v2.y+v2.z*v2.z+v2.w*v2.w;
  #pragma unroll
  for (int o = 32; o; o >>= 1){ s += __shfl_xor(s, o); ss += __shfl_xor(ss, o); }
  float mean = s * (1.f/768.f);
  float var  = ss * (1.f/768.f) - mean*mean;
  float rstd = rsqrtf(var + 1e-5f);
  const float* gg = isT ? t_g : s_g;
  const float* bb = isT ? t_b : s_b;
  #pragma unroll
  for (int k = 0; k < 3; ++k){
    int c = lane*4 + k*256;
    float4 v = (k==0) ? v0 : (k==1) ? v1 : v2;
    float4 gv = *(const float4*)(gg + c);
    float4 bv = *(const float4*)(bb + c);
    float o0 = (v.x-mean)*rstd*gv.x + bv.x;
    float o1 = (v.y-mean)*rstd*gv.y + bv.y;
    float o2 = (v.z-mean)*rstd*gv.z + bv.z;
    float o3 = (v.w-mean)*rstd*gv.w + bv.w;
    ushort4 ub; ub.x=f2bf(o0); ub.y=f2bf(o1); ub.z=f2bf(o2); ub.w=f2bf(o3);
    if (isT){
      float4 ov; ov.x=o0; ov.y=o1; ov.z=o2; ov.w=o3;
      *(float4*)(th + (size_t)row * D768 + c) = ov;
      *(ushort4*)(gcat + (size_t)row * 1568 + c) = ub;
    } else {
      *(ushort4*)(sh + (size_t)row * D768 + c) = ub;
    }
  }
}

// ---------- 4-wave MFMA GEMM (tproj), 128xBN tile, depth-3 ring ----------
template<int MODE, int BN>
__launch_bounds__(256)
__global__ void k_gemm(const unsigned short* __restrict__ A, int lda,
                       const unsigned short* __restrict__ Bt, int ldb,
                       int ksteps, int ntn,
                       const float* __restrict__ tproj,
                       const float* __restrict__ b1,
                       const float* __restrict__ w2,
                       float* __restrict__ out){
  constexpr int NJ  = BN / 32;
  constexpr int BCH = BN / 64;
  __shared__ __align__(16) unsigned short As[3][128*32];
  __shared__ __align__(16) unsigned short Bs[3][BN*32];
  const int cpx = gridDim.x >> 3;
  const int logical = ((int)blockIdx.x & 7) * cpx + ((int)blockIdx.x >> 3);
  const int m0 = (logical / ntn) * 128, n0 = (logical % ntn) * BN;
  const int t = threadIdx.x, lane = t & 63, w = t >> 6;
  const int wrow = (w >> 1) * 64, wcol = (w & 1) * (BN/2);
  const int lo16 = lane & 15;
  const int hs = ((lane >> 4) ^ ((lo16 >> 1) & 3)) * 8;
  const int crow = lane >> 2;
  const int cseg = (((lane & 3) ^ ((lane >> 3) & 3)) * 8);
  const unsigned short* ga = A  + (size_t)(m0 + w*32 + crow) * lda + cseg;
  const unsigned short* gb = Bt + (size_t)(n0 + w*(BN/4) + crow) * ldb + cseg;
  f32x4 acc[4][NJ] = {};

#define STAGEK(BUF, KS) do {                                                   \
    const unsigned short* gak_ = ga + (size_t)(KS)*32;                         \
    const unsigned short* gbk_ = gb + (size_t)(KS)*32;                         \
    _Pragma("unroll")                                                          \
    for (int c = 0; c < 2; ++c)                                                \
      gload16(gak_ + (size_t)(c*16)*lda, &As[BUF][w*1024 + c*512]);            \
    _Pragma("unroll")                                                          \
    for (int c = 0; c < BCH; ++c)                                              \
      gload16(gbk_ + (size_t)(c*16)*ldb, &Bs[BUF][w*(BN/4)*32 + c*512]);       \
  } while (0)

#define COMPUTEK(BUF) do {                                                     \
    const unsigned short* pa_ = &As[BUF][(wrow + lo16)*32 + hs];               \
    const unsigned short* pb_ = &Bs[BUF][(wcol + lo16)*32 + hs];               \
    short8 af_[4], bf_[NJ];                                                    \
    _Pragma("unroll")                                                          \
    for (int i = 0; i < 4; ++i) af_[i] = *(const short8*)(pa_ + i*16*32);      \
    _Pragma("unroll")                                                          \
    for (int j = 0; j < NJ; ++j) bf_[j] = *(const short8*)(pb_ + j*16*32);     \
    _Pragma("unroll")                                                          \
    for (int i = 0; i < 4; ++i)                                                \
      _Pragma("unroll")                                                        \
      for (int j = 0; j < NJ; ++j)                                             \
        acc[i][j] = __builtin_amdgcn_mfma_f32_16x16x32_bf16(af_[i], bf_[j], acc[i][j], 0, 0, 0); \
  } while (0)

#define WAITN(n) asm volatile("s_waitcnt vmcnt(" #n ")" ::: "memory")

  {
    int pro = ksteps < 2 ? ksteps : 2;
    for (int p = 0; p < pro; ++p) STAGEK(p, p);
  }
  for (int ks = 0; ks < ksteps; ++ks){
    int rem = ksteps - ks;
    if (rem >= 2){ if constexpr (BCH == 2) WAITN(4); else WAITN(3); }
    else WAITN(0);
    __builtin_amdgcn_s_barrier();
    __builtin_amdgcn_sched_barrier(0);
    if (ks + 2 < ksteps) STAGEK((ks + 2) % 3, ks + 2);
    COMPUTEK(ks % 3);
  }
#undef STAGEK
#undef COMPUTEK
#undef WAITN

  if (MODE == 0){
    #pragma unroll
    for (int i = 0; i < 4; ++i)
      #pragma unroll
      for (int reg = 0; reg < 4; ++reg){
        int row = m0 + wrow + i*16 + ((lane >> 4) << 2) + reg;
        float* orow = out + (size_t)row * D768 + n0 + wcol + (lane & 15);
        #pragma unroll
        for (int j = 0; j < NJ; ++j) orow[j*16] = acc[i][j][reg];
      }
  } else {
    #pragma unroll
    for (int i = 0; i < 4; ++i)
      #pragma unroll
      for (int reg = 0; reg < 4; ++reg){
        int row = m0 + wrow + i*16 + ((lane >> 4) << 2) + reg;
        const float* tp = nullptr;
        if (MODE == 1){
          int trow = ((row >> 13) << 10) | (row & 1023);
          tp = tproj + (size_t)trow * D768;
        }
        float contrib = 0.f;
        #pragma unroll
        for (int j = 0; j < NJ; ++j){
          int n = n0 + wcol + j*16 + (lane & 15);
          float v = acc[i][j][reg] + b1[n];
          if (MODE == 1) v += tp[n];
          contrib += gelu_f(v) * w2[n];
        }
        for (int o = 8; o; o >>= 1) contrib += __shfl_xor(contrib, o);
        if ((lane & 15) == 0) atomicAdd(&out[row], contrib);
      }
  }
}

// ---------- 8-wave MFMA GEMM (score), 128x128 tile, depth-3 ring ----------
__launch_bounds__(512)
__global__ void k_gemm8(const unsigned short* __restrict__ A, int lda,
                        const unsigned short* __restrict__ Bt, int ldb,
                        int ksteps, int ntn,
                        const float* __restrict__ tproj,
                        const float* __restrict__ b1,
                        const float* __restrict__ w2,
                        float* __restrict__ out){
  __shared__ __align__(16) unsigned short As[3][128*32];
  __shared__ __align__(16) unsigned short Bs[3][128*32];
  const int cpx = gridDim.x >> 3;
  const int logical = ((int)blockIdx.x & 7) * cpx + ((int)blockIdx.x >> 3);
  const int m0 = (logical / ntn) * 128, n0 = (logical % ntn) * 128;
  const int t = threadIdx.x, lane = t & 63, w = t >> 6; // 8 waves
  const int wrow = (w >> 2) * 64, wcol = (w & 3) * 32;
  const int lo16 = lane & 15;
  const int hs = ((lane >> 4) ^ ((lo16 >> 1) & 3)) * 8;
  const int crow = lane >> 2;
  const int cseg = (((lane & 3) ^ ((lane >> 3) & 3)) * 8);
  const unsigned short* ga = A  + (size_t)(m0 + w*16 + crow) * lda + cseg;
  const unsigned short* gb = Bt + (size_t)(n0 + w*16 + crow) * ldb + cseg;
  f32x4 acc[4][2] = {};

#define STAGEK(BUF, KS) do {                                                   \
    gload16(ga + (size_t)(KS)*32, &As[BUF][w*512]);                            \
    gload16(gb + (size_t)(KS)*32, &Bs[BUF][w*512]);                            \
  } while (0)

#define COMPUTEK(BUF) do {                                                     \
    const unsigned short* pa_ = &As[BUF][(wrow + lo16)*32 + hs];               \
    const unsigned short* pb_ = &Bs[BUF][(wcol + lo16)*32 + hs];               \
    short8 af_[4], bf_[2];                                                     \
    _Pragma("unroll")                                                          \
    for (int i = 0; i < 4; ++i) af_[i] = *(const short8*)(pa_ + i*16*32);      \
    _Pragma("unroll")                                                          \
    for (int j = 0; j < 2; ++j) bf_[j] = *(const short8*)(pb_ + j*16*32);      \
    _Pragma("unroll")                                                          \
    for (int i = 0; i < 4; ++i)                                                \
      _Pragma("unroll")                                                        \
      for (int j = 0; j < 2; ++j)                                              \
        acc[i][j] = __builtin_amdgcn_mfma_f32_16x16x32_bf16(af_[i], bf_[j], acc[i][j], 0, 0, 0); \
  } while (0)

#define WAITN(n) asm volatile("s_waitcnt vmcnt(" #n ")" ::: "memory")

  {
    int pro = ksteps < 2 ? ksteps : 2;
    for (int p = 0; p < pro; ++p) STAGEK(p, p);
  }
  for (int ks = 0; ks < ksteps; ++ks){
    int rem = ksteps - ks;
    if (rem >= 2) WAITN(2);
    else WAITN(0);
    __builtin_amdgcn_s_barrier();
    __builtin_amdgcn_sched_barrier(0);
    if (ks + 2 < ksteps) STAGEK((ks + 2) % 3, ks + 2);
    COMPUTEK(ks % 3);
  }
#undef STAGEK
#undef COMPUTEK
#undef WAITN

  #pragma unroll
  for (int i = 0; i < 4; ++i)
    #pragma unroll
    for (int reg = 0; reg < 4; ++reg){
      int row = m0 + wrow + i*16 + ((lane >> 4) << 2) + reg;
      int trow = ((row >> 13) << 10) | (row & 1023);
      const float* tp = tproj + (size_t)trow * D768;
      float contrib = 0.f;
      #pragma unroll
      for (int j = 0; j < 2; ++j){
        int n = n0 + wcol + j*16 + lo16;
        float v = acc[i][j][reg] + b1[n] + tp[n];
        contrib += gelu_f(v) * w2[n];
      }
      for (int o = 8; o; o >>= 1) contrib += __shfl_xor(contrib, o);
      if (lo16 == 0) atomicAdd(&out[row], contrib);
    }
}

// ---------- 8-wave MFMA GEMM (gate), 128x64 tile, depth-3 ring ----------
// Wave grid 2M x 4N: each wave 64 rows x 16 cols (acc[4], NJ=1). LDS 36KB ->
// 4 blocks/CU. Staging: all 8 waves stage 1 A-chunk (16 rows); waves 0..3 also
// stage 1 B-chunk; per-wave counted vmcnt (2 for w<4, 1 for w>=4).
__launch_bounds__(512)
__global__ void k_gemm8g(const unsigned short* __restrict__ A, int lda,
                         const unsigned short* __restrict__ Bt, int ldb,
                         int ksteps, int ntn,
                         const float* __restrict__ b1,
                         const float* __restrict__ w2,
                         float* __restrict__ out){
  __shared__ __align__(16) unsigned short As[3][128*32];
  __shared__ __align__(16) unsigned short Bs[3][64*32];
  const int cpx = gridDim.x >> 3;
  const int logical = ((int)blockIdx.x & 7) * cpx + ((int)blockIdx.x >> 3);
  const int m0 = (logical / ntn) * 128, n0 = (logical % ntn) * 64;
  const int t = threadIdx.x, lane = t & 63, w = t >> 6; // 8 waves
  const int wrow = (w >> 2) * 64, wcol = (w & 3) * 16;
  const int lo16 = lane & 15;
  const int hs = ((lane >> 4) ^ ((lo16 >> 1) & 3)) * 8;
  const int crow = lane >> 2;
  const int cseg = (((lane & 3) ^ ((lane >> 3) & 3)) * 8);
  const unsigned short* ga = A  + (size_t)(m0 + w*16 + crow) * lda + cseg;
  const unsigned short* gb = Bt + (size_t)(n0 + w*16 + crow) * ldb + cseg; // valid for w<4
  f32x4 acc[4] = {};

#define STAGEK(BUF, KS) do {                                                   \
    gload16(ga + (size_t)(KS)*32, &As[BUF][w*512]);                            \
    if (w < 4) gload16(gb + (size_t)(KS)*32, &Bs[BUF][w*512]);                 \
  } while (0)

#define COMPUTEK(BUF) do {                                                     \
    const unsigned short* pa_ = &As[BUF][(wrow + lo16)*32 + hs];               \
    const unsigned short* pb_ = &Bs[BUF][(wcol + lo16)*32 + hs];               \
    short8 af_[4], bf_;                                                        \
    _Pragma("unroll")                                                          \
    for (int i = 0; i < 4; ++i) af_[i] = *(const short8*)(pa_ + i*16*32);      \
    bf_ = *(const short8*)pb_;                                                 \
    _Pragma("unroll")                                                          \
    for (int i = 0; i < 4; ++i)                                                \
      acc[i] = __builtin_amdgcn_mfma_f32_16x16x32_bf16(af_[i], bf_, acc[i], 0, 0, 0); \
  } while (0)

#define WAITN(n) asm volatile("s_waitcnt vmcnt(" #n ")" ::: "memory")

  {
    int pro = ksteps < 2 ? ksteps : 2;
    for (int p = 0; p < pro; ++p) STAGEK(p, p);
  }
  for (int ks = 0; ks < ksteps; ++ks){
    int rem = ksteps - ks;
    if (rem >= 2){ if (w < 4) WAITN(2); else WAITN(1); }
    else WAITN(0);
    __builtin_amdgcn_s_barrier();
    __builtin_amdgcn_sched_barrier(0);
    if (ks + 2 < ksteps) STAGEK((ks + 2) % 3, ks + 2);
    COMPUTEK(ks % 3);
  }
#undef STAGEK
#undef COMPUTEK
#undef WAITN

  // gate epilogue: +b1, gelu, *w2, 16-lane reduce, atomicAdd
  #pragma unroll
  for (int i = 0; i < 4; ++i)
    #pragma unroll
    for (int reg = 0; reg < 4; ++reg){
      int row = m0 + wrow + i*16 + ((lane >> 4) << 2) + reg;
      int n = n0 + wcol + lo16;
      float v = acc[i][reg] + b1[n];
      float contrib = gelu_f(v) * w2[n];
      for (int o = 8; o; o >>= 1) contrib += __shfl_xor(contrib, o);
      if (lo16 == 0) atomicAdd(&out[row], contrib);
    }
}

// ---------- masked softmax over S=8 + weighted summary -> gcat[:,768:1568] (bf16) ----------
__global__ void k_smx(const float* __restrict__ scores, const void* __restrict__ maskp,
                      const int* __restrict__ flag, const unsigned short* __restrict__ sh,
                      const float* __restrict__ feat,
                      unsigned short* __restrict__ gcat){
  int bt = blockIdx.x;
  int b = bt >> 10, tt = bt & 1023;
  int t = threadIdx.x; // 192
  int f = *flag;
  float sc[8], mk[8];
  #pragma unroll
  for (int s = 0; s < 8; ++s){
    size_t idx = ((size_t)(b*8 + s) << 10) + tt;
    bool m = f ? (((const int*)maskp)[idx] != 0)
               : (((const unsigned char*)maskp)[idx] != 0);
    mk[s] = m ? 1.f : 0.f;
    float v = scores[idx];
    sc[s] = m ? v : -10000.f;
  }
  float mx = sc[0];
  #pragma unroll
  for (int s = 1; s < 8; ++s) mx = fmaxf(mx, sc[s]);
  float e[8], sum = 0.f;
  #pragma unroll
  for (int s = 0; s < 8; ++s){ e[s] = __expf(sc[s] - mx); sum += e[s]; }
  float inv = 1.f / sum;
  float wv[8], sum2 = 0.f;
  #pragma unroll
  for (int s = 0; s < 8; ++s){ wv[s] = e[s] * inv * mk[s]; sum2 += wv[s]; }
  float inv2 = 1.f / fmaxf(sum2, 1e-8f);
  #pragma unroll
  for (int s = 0; s < 8; ++s) wv[s] *= inv2;
  float a0=0.f, a1=0.f, a2=0.f, a3=0.f;
  #pragma unroll
  for (int s = 0; s < 8; ++s){
    const unsigned short* p = sh + (((size_t)(b*8+s) << 10) + tt) * D768 + t*4;
    ushort4 u = *(const ushort4*)p;
    float ws = wv[s];
    a0 += ws * bf2f(u.x); a1 += ws * bf2f(u.y); a2 += ws * bf2f(u.z); a3 += ws * bf2f(u.w);
  }
  ushort4 ub; ub.x=f2bf(a0); ub.y=f2bf(a1); ub.z=f2bf(a2); ub.w=f2bf(a3);
  *(ushort4*)(gcat + (size_t)bt * 1568 + 768 + t*4) = ub;
  if (t < 8){
    int c = 1536 + t*4;
    float4 fv = make_float4(0.f, 0.f, 0.f, 0.f);
    if (c < 1552) fv = *(const float4*)(feat + (size_t)bt * 16 + (c - 1536));
    ushort4 uf; uf.x=f2bf(fv.x); uf.y=f2bf(fv.y); uf.z=f2bf(fv.z); uf.w=f2bf(fv.w);
    *(ushort4*)(gcat + (size_t)bt * 1568 + c) = uf;
  }
}

// ---------- gate=sigmoid(gacc); x=(2-g)*th+g*summary(bf16 from gcat); out=LN(x) ----------
__global__ void k_final(const float* __restrict__ th, const unsigned short* __restrict__ gcat,
                        const float* __restrict__ gacc, const float* __restrict__ og,
                        const float* __restrict__ ob, float* __restrict__ out,
                        float* __restrict__ outg){
  int r = blockIdx.x, t = threadIdx.x; // 192
  float gv = 1.f / (1.f + __expf(-gacc[r]));
  if (t == 0) outg[r] = gv;
  float4 tv = *(const float4*)(th + (size_t)r * D768 + t*4);
  ushort4 su = *(const ushort4*)(gcat + (size_t)r * 1568 + 768 + t*4);
  float s0 = bf2f(su.x), s1 = bf2f(su.y), s2 = bf2f(su.z), s3 = bf2f(su.w);
  float x0 = (2.f-gv)*tv.x + gv*s0;
  float x1 = (2.f-gv)*tv.y + gv*s1;
  float x2 = (2.f-gv)*tv.z + gv*s2;
  float x3 = (2.f-gv)*tv.w + gv*s3;
  float s = x0+x1+x2+x3, ss = x0*x0+x1*x1+x2*x2+x3*x3;
  for (int o = 32; o; o >>= 1){ s += __shfl_down(s,o); ss += __shfl_down(ss,o); }
  __shared__ float sb[6];
  int wid = t >> 6;
  if ((t&63)==0){ sb[wid]=s; sb[3+wid]=ss; }
  __syncthreads();
  s = sb[0]+sb[1]+sb[2]; ss = sb[3]+sb[4]+sb[5];
  float mean = s*(1.f/768.f), var = ss*(1.f/768.f)-mean*mean;
  float rstd = rsqrtf(var + 1e-5f);
  float4 gvv = *(const float4*)(og + t*4);
  float4 bvv = *(const float4*)(ob + t*4);
  float4 ov;
  ov.x = (x0-mean)*rstd*gvv.x + bvv.x;
  ov.y = (x1-mean)*rstd*gvv.y + bvv.y;
  ov.z = (x2-mean)*rstd*gvv.z + bvv.z;
  ov.w = (x3-mean)*rstd*gvv.w + bvv.w;
  *(float4*)(out + (size_t)r * D768 + t*4) = ov;
}

extern "C" void kernel_launch(void* const* d_in, const int* in_sizes, int n_in,
                              void* d_out, int out_size, void* d_ws, size_t ws_size,
                              hipStream_t stream){
  const float* target = (const float*)d_in[0];
  const float* support= (const float*)d_in[1];
  const void*  maskp  = d_in[2];
  const float* feat   = (const float*)d_in[3];
  const float* t_g = (const float*)d_in[4];
  const float* t_b = (const float*)d_in[5];
  const float* s_g = (const float*)d_in[6];
  const float* s_b = (const float*)d_in[7];
  const float* o_g = (const float*)d_in[8];
  const float* o_b = (const float*)d_in[9];
  const float* sw1 = (const float*)d_in[10];
  const float* sb1 = (const float*)d_in[11];
  const float* sw2 = (const float*)d_in[12];
  const float* sb2 = (const float*)d_in[13];
  const float* gw1 = (const float*)d_in[14];
  const float* gb1 = (const float*)d_in[15];
  const float* gw2 = (const float*)d_in[16];
  const float* gb2 = (const float*)d_in[17];

  char* wsb = (char*)d_ws;
  size_t off = 0;
  auto alloc = [&](size_t bytes)->void*{
    void* p = wsb + off; off += (bytes + 255) & ~(size_t)255; return p;
  };
  float* th            = (float*)alloc(4096ull*768*4);
  unsigned short* sh   = (unsigned short*)alloc(32768ull*768*2);
  float* tproj         = (float*)alloc(4096ull*768*4);
  unsigned short* gcat = (unsigned short*)alloc(4096ull*1568*2);
  unsigned short* WtA  = (unsigned short*)alloc(768ull*768*2);
  unsigned short* WtB  = (unsigned short*)alloc(768ull*768*2);
  unsigned short* WtG  = (unsigned short*)alloc(768ull*1568*2);
  float* scores        = (float*)alloc(32768ull*4);
  float* gacc          = (float*)alloc(4096ull*4);
  int*   flag          = (int*)alloc(256);

  float* outm = (float*)d_out;       // (B,T,D)
  float* outg = outm + 4096ull*768;  // (B,T)

  // init + maskdet + weight transposes + target LN + support LN (one launch)
  k_mega<<<11672, 256, 0, stream>>>(target, support, t_g, t_b, s_g, s_b,
                                    th, gcat, sh, sw1, gw1, WtA, WtB, WtG,
                                    scores, sb2, gacc, gb2,
                                    (const unsigned char*)maskp, flag);
  // tproj = th @ W1a   (384 blocks, ntn=12)
  k_gemm<0,64><<<384, 256, 0, stream>>>(gcat, 1568, WtA, 768, 24, 12,
                                        nullptr, nullptr, nullptr, tproj);
  // scores += rowsum(gelu(sh@W1b + tproj + b1) * w2)   (8-wave, 1536 blocks, ntn=6)
  k_gemm8<<<1536, 512, 0, stream>>>(sh, 768, WtB, 768, 24, 6,
                                    tproj, sb1, sw2, scores);
  // masked softmax + summary -> gcat[:, 768:1568]
  k_smx<<<4096, 192, 0, stream>>>(scores, maskp, flag, sh, feat, gcat);
  // gate_acc += rowsum(gelu(gcat@gW1 + gb1) * gw2)   (8-wave, 384 blocks, ntn=12)
  k_gemm8g<<<384, 512, 0, stream>>>(gcat, 1568, WtG, 1568, 49, 12,
                                    gb1, gw2, gacc);
  k_final<<<4096, 192, 0, stream>>>(th, gcat, gacc, o_g, o_b, outm, outg);
}

// Round 15
// 172.522 us; speedup vs baseline: 1.0472x; 1.0098x over previous
//
#include <hip/hip_runtime.h>
#include <hip/hip_bf16.h>

#define D768 768

typedef __attribute__((ext_vector_type(8))) short short8;
typedef __attribute__((ext_vector_type(4))) float f32x4;

__device__ __forceinline__ unsigned short f2bf(float f){
  union { float f; unsigned u; } v; v.f = f;
  unsigned r = v.u + 0x7FFFu + ((v.u >> 16) & 1u);
  return (unsigned short)(r >> 16);
}
__device__ __forceinline__ float bf2f(unsigned short u){
  union { unsigned u; float f; } v; v.u = ((unsigned)u) << 16;
  return v.f;
}
// exact-erf GELU via Abramowitz-Stegun 7.1.26 (|eps| <= 1.5e-7), ~13 VALU + exp + rcp
__device__ __forceinline__ float gelu_f(float x){
  float y = fabsf(x) * 0.7071067811865475f;
  float t = __builtin_amdgcn_rcpf(fmaf(0.3275911f, y, 1.0f));
  float p = fmaf(fmaf(fmaf(fmaf(1.061405429f, t, -1.453152027f), t, 1.421413741f),
                      t, -0.284496736f), t, 0.254829592f) * t;
  float e = __expf(-y * y);
  float erf_abs = fmaf(-p, e, 1.0f);
  float erfv = copysignf(erf_abs, x);
  return 0.5f * x * (1.0f + erfv);
}
__device__ __forceinline__ void gload16(const void* g, void* l){
  __builtin_amdgcn_global_load_lds((const __attribute__((address_space(1))) void*)g,
                                   (__attribute__((address_space(3))) void*)l, 16, 0, 0);
}

// ---------- MEGA kernel: init (0..127) + weight transpose (128..2455) +
// target LN (2456..3479, 4 rows/block) + support LN (3480..11671, 4 rows/block).
__global__ __launch_bounds__(256)
void k_mega(const float* __restrict__ target, const float* __restrict__ support,
            const float* __restrict__ t_g, const float* __restrict__ t_b,
            const float* __restrict__ s_g, const float* __restrict__ s_b,
            float* __restrict__ th, unsigned short* __restrict__ gcat,
            unsigned short* __restrict__ sh,
            const float* __restrict__ sw1, const float* __restrict__ gw1,
            unsigned short* __restrict__ WtA, unsigned short* __restrict__ WtB,
            unsigned short* __restrict__ WtG,
            float* __restrict__ scores, const float* __restrict__ sb2,
            float* __restrict__ gacc, const float* __restrict__ gb2,
            const unsigned char* __restrict__ m, int* __restrict__ flag){
  int blk = blockIdx.x;
  int t = threadIdx.x;
  if (blk < 128){
    int i = blk * 256 + t;
    if (i < 32768) scores[i] = sb2[0];
    if (i < 4096)  gacc[i]   = gb2[0];
    if (blk == 0){
      __shared__ int s;
      if (t == 0) s = 0;
      __syncthreads();
      int nz = 0;
      for (int j = t; j < 2048; j += 256) nz += (m[4*j+1] != 0);
      atomicAdd(&s, nz);
      __syncthreads();
      if (t == 0) *flag = (s == 0) ? 1 : 0; // 1 => 4-byte mask elems
    }
    return;
  }
  if (blk < 2456){
    int tile = blk - 128;
    const float* W; unsigned short* Wt; int Kin, Kpad;
    if (tile < 576)      { W = sw1;              Wt = WtA; Kin = 768;  Kpad = 768;  }
    else if (tile < 1152){ W = sw1 + 768ull*768; Wt = WtB; Kin = 768;  Kpad = 768;  tile -= 576; }
    else                 { W = gw1;              Wt = WtG; Kin = 1552; Kpad = 1568; tile -= 1152; }
    int ntk = Kpad >> 5;
    int k0 = (tile % ntk) << 5, n0 = (tile / ntk) << 5;
    __shared__ float ts[32][33];
    int tx = t & 31, ty = t >> 5; // 32x8
    #pragma unroll
    for (int r = 0; r < 4; ++r){
      int k = k0 + ty + r*8;
      ts[ty + r*8][tx] = (k < Kin) ? W[(size_t)k * D768 + n0 + tx] : 0.f;
    }
    __syncthreads();
    #pragma unroll
    for (int r = 0; r < 4; ++r){
      int n = n0 + ty + r*8;
      Wt[(size_t)n * Kpad + k0 + tx] = f2bf(ts[tx][ty + r*8]);
    }
    return;
  }
  // LayerNorm: 1 wave per row, 4 rows per block
  bool isT = blk < 3480;
  int row = (isT ? (blk - 2456) : (blk - 3480)) * 4 + (t >> 6);
  int lane = t & 63;
  const float* xr = (isT ? target : support) + (size_t)row * D768;
  float4 v0 = *(const float4*)(xr + lane*4);
  float4 v1 = *(const float4*)(xr + 256 + lane*4);
  float4 v2 = *(const float4*)(xr + 512 + lane*4);
  float s  = v0.x+v0.y+v0.z+v0.w + v1.x+v1.y+v1.z+v1.w + v2.x+v2.y+v2.z+v2.w;
  float ss = v0.x*v0.x+v0.y*v0.y+v0.z*v0.z+v0.w*v0.w
           + v1.x*v1.x+v1.y*v1.y+v1.z*v1.z+v1.w*v1.w
           + v2.x*v2.x+v2.y*v2.y+v2.z*v2.z+v2.w*v2.w;
  #pragma unroll
  for (int o = 32; o; o >>= 1){ s += __shfl_xor(s, o); ss += __shfl_xor(ss, o); }
  float mean = s * (1.f/768.f);
  float var  = ss * (1.f/768.f) - mean*mean;
  float rstd = rsqrtf(var + 1e-5f);
  const float* gg = isT ? t_g : s_g;
  const float* bb = isT ? t_b : s_b;
  #pragma unroll
  for (int k = 0; k < 3; ++k){
    int c = lane*4 + k*256;
    float4 v = (k==0) ? v0 : (k==1) ? v1 : v2;
    float4 gv = *(const float4*)(gg + c);
    float4 bv = *(const float4*)(bb + c);
    float o0 = (v.x-mean)*rstd*gv.x + bv.x;
    float o1 = (v.y-mean)*rstd*gv.y + bv.y;
    float o2 = (v.z-mean)*rstd*gv.z + bv.z;
    float o3 = (v.w-mean)*rstd*gv.w + bv.w;
    ushort4 ub; ub.x=f2bf(o0); ub.y=f2bf(o1); ub.z=f2bf(o2); ub.w=f2bf(o3);
    if (isT){
      float4 ov; ov.x=o0; ov.y=o1; ov.z=o2; ov.w=o3;
      *(float4*)(th + (size_t)row * D768 + c) = ov;
      *(ushort4*)(gcat + (size_t)row * 1568 + c) = ub;
    } else {
      *(ushort4*)(sh + (size_t)row * D768 + c) = ub;
    }
  }
}

// ---------- 4-wave MFMA GEMM (tproj), 128xBN tile, depth-3 ring ----------
template<int MODE, int BN>
__launch_bounds__(256)
__global__ void k_gemm(const unsigned short* __restrict__ A, int lda,
                       const unsigned short* __restrict__ Bt, int ldb,
                       int ksteps, int ntn,
                       const float* __restrict__ tproj,
                       const float* __restrict__ b1,
                       const float* __restrict__ w2,
                       float* __restrict__ out){
  constexpr int NJ  = BN / 32;
  constexpr int BCH = BN / 64;
  __shared__ __align__(16) unsigned short As[3][128*32];
  __shared__ __align__(16) unsigned short Bs[3][BN*32];
  const int cpx = gridDim.x >> 3;
  const int logical = ((int)blockIdx.x & 7) * cpx + ((int)blockIdx.x >> 3);
  const int m0 = (logical / ntn) * 128, n0 = (logical % ntn) * BN;
  const int t = threadIdx.x, lane = t & 63, w = t >> 6;
  const int wrow = (w >> 1) * 64, wcol = (w & 1) * (BN/2);
  const int lo16 = lane & 15;
  const int hs = ((lane >> 4) ^ ((lo16 >> 1) & 3)) * 8;
  const int crow = lane >> 2;
  const int cseg = (((lane & 3) ^ ((lane >> 3) & 3)) * 8);
  const unsigned short* ga = A  + (size_t)(m0 + w*32 + crow) * lda + cseg;
  const unsigned short* gb = Bt + (size_t)(n0 + w*(BN/4) + crow) * ldb + cseg;
  f32x4 acc[4][NJ] = {};

#define STAGEK(BUF, KS) do {                                                   \
    const unsigned short* gak_ = ga + (size_t)(KS)*32;                         \
    const unsigned short* gbk_ = gb + (size_t)(KS)*32;                         \
    _Pragma("unroll")                                                          \
    for (int c = 0; c < 2; ++c)                                                \
      gload16(gak_ + (size_t)(c*16)*lda, &As[BUF][w*1024 + c*512]);            \
    _Pragma("unroll")                                                          \
    for (int c = 0; c < BCH; ++c)                                              \
      gload16(gbk_ + (size_t)(c*16)*ldb, &Bs[BUF][w*(BN/4)*32 + c*512]);       \
  } while (0)

#define COMPUTEK(BUF) do {                                                     \
    const unsigned short* pa_ = &As[BUF][(wrow + lo16)*32 + hs];               \
    const unsigned short* pb_ = &Bs[BUF][(wcol + lo16)*32 + hs];               \
    short8 af_[4], bf_[NJ];                                                    \
    _Pragma("unroll")                                                          \
    for (int i = 0; i < 4; ++i) af_[i] = *(const short8*)(pa_ + i*16*32);      \
    _Pragma("unroll")                                                          \
    for (int j = 0; j < NJ; ++j) bf_[j] = *(const short8*)(pb_ + j*16*32);     \
    __builtin_amdgcn_s_setprio(1);                                             \
    _Pragma("unroll")                                                          \
    for (int i = 0; i < 4; ++i)                                                \
      _Pragma("unroll")                                                        \
      for (int j = 0; j < NJ; ++j)                                             \
        acc[i][j] = __builtin_amdgcn_mfma_f32_16x16x32_bf16(af_[i], bf_[j], acc[i][j], 0, 0, 0); \
    __builtin_amdgcn_s_setprio(0);                                             \
  } while (0)

#define WAITN(n) asm volatile("s_waitcnt vmcnt(" #n ")" ::: "memory")

  {
    int pro = ksteps < 2 ? ksteps : 2;
    for (int p = 0; p < pro; ++p) STAGEK(p, p);
  }
  for (int ks = 0; ks < ksteps; ++ks){
    int rem = ksteps - ks;
    if (rem >= 2){ if constexpr (BCH == 2) WAITN(4); else WAITN(3); }
    else WAITN(0);
    __builtin_amdgcn_s_barrier();
    __builtin_amdgcn_sched_barrier(0);
    if (ks + 2 < ksteps) STAGEK((ks + 2) % 3, ks + 2);
    COMPUTEK(ks % 3);
  }
#undef STAGEK
#undef COMPUTEK
#undef WAITN

  if (MODE == 0){
    #pragma unroll
    for (int i = 0; i < 4; ++i)
      #pragma unroll
      for (int reg = 0; reg < 4; ++reg){
        int row = m0 + wrow + i*16 + ((lane >> 4) << 2) + reg;
        float* orow = out + (size_t)row * D768 + n0 + wcol + (lane & 15);
        #pragma unroll
        for (int j = 0; j < NJ; ++j) orow[j*16] = acc[i][j][reg];
      }
  } else {
    #pragma unroll
    for (int i = 0; i < 4; ++i)
      #pragma unroll
      for (int reg = 0; reg < 4; ++reg){
        int row = m0 + wrow + i*16 + ((lane >> 4) << 2) + reg;
        const float* tp = nullptr;
        if (MODE == 1){
          int trow = ((row >> 13) << 10) | (row & 1023);
          tp = tproj + (size_t)trow * D768;
        }
        float contrib = 0.f;
        #pragma unroll
        for (int j = 0; j < NJ; ++j){
          int n = n0 + wcol + j*16 + (lane & 15);
          float v = acc[i][j][reg] + b1[n];
          if (MODE == 1) v += tp[n];
          contrib += gelu_f(v) * w2[n];
        }
        for (int o = 8; o; o >>= 1) contrib += __shfl_xor(contrib, o);
        if ((lane & 15) == 0) atomicAdd(&out[row], contrib);
      }
  }
}

// ---------- 8-wave MFMA GEMM (score), 128x128 tile, depth-3 ring ----------
__launch_bounds__(512)
__global__ void k_gemm8(const unsigned short* __restrict__ A, int lda,
                        const unsigned short* __restrict__ Bt, int ldb,
                        int ksteps, int ntn,
                        const float* __restrict__ tproj,
                        const float* __restrict__ b1,
                        const float* __restrict__ w2,
                        float* __restrict__ out){
  __shared__ __align__(16) unsigned short As[3][128*32];
  __shared__ __align__(16) unsigned short Bs[3][128*32];
  const int cpx = gridDim.x >> 3;
  const int logical = ((int)blockIdx.x & 7) * cpx + ((int)blockIdx.x >> 3);
  const int m0 = (logical / ntn) * 128, n0 = (logical % ntn) * 128;
  const int t = threadIdx.x, lane = t & 63, w = t >> 6; // 8 waves
  const int wrow = (w >> 2) * 64, wcol = (w & 3) * 32;
  const int lo16 = lane & 15;
  const int hs = ((lane >> 4) ^ ((lo16 >> 1) & 3)) * 8;
  const int crow = lane >> 2;
  const int cseg = (((lane & 3) ^ ((lane >> 3) & 3)) * 8);
  const unsigned short* ga = A  + (size_t)(m0 + w*16 + crow) * lda + cseg;
  const unsigned short* gb = Bt + (size_t)(n0 + w*16 + crow) * ldb + cseg;
  f32x4 acc[4][2] = {};

#define STAGEK(BUF, KS) do {                                                   \
    gload16(ga + (size_t)(KS)*32, &As[BUF][w*512]);                            \
    gload16(gb + (size_t)(KS)*32, &Bs[BUF][w*512]);                            \
  } while (0)

#define COMPUTEK(BUF) do {                                                     \
    const unsigned short* pa_ = &As[BUF][(wrow + lo16)*32 + hs];               \
    const unsigned short* pb_ = &Bs[BUF][(wcol + lo16)*32 + hs];               \
    short8 af_[4], bf_[2];                                                     \
    _Pragma("unroll")                                                          \
    for (int i = 0; i < 4; ++i) af_[i] = *(const short8*)(pa_ + i*16*32);      \
    _Pragma("unroll")                                                          \
    for (int j = 0; j < 2; ++j) bf_[j] = *(const short8*)(pb_ + j*16*32);      \
    __builtin_amdgcn_s_setprio(1);                                             \
    _Pragma("unroll")                                                          \
    for (int i = 0; i < 4; ++i)                                                \
      _Pragma("unroll")                                                        \
      for (int j = 0; j < 2; ++j)                                              \
        acc[i][j] = __builtin_amdgcn_mfma_f32_16x16x32_bf16(af_[i], bf_[j], acc[i][j], 0, 0, 0); \
    __builtin_amdgcn_s_setprio(0);                                             \
  } while (0)

#define WAITN(n) asm volatile("s_waitcnt vmcnt(" #n ")" ::: "memory")

  {
    int pro = ksteps < 2 ? ksteps : 2;
    for (int p = 0; p < pro; ++p) STAGEK(p, p);
  }
  for (int ks = 0; ks < ksteps; ++ks){
    int rem = ksteps - ks;
    if (rem >= 2) WAITN(2);
    else WAITN(0);
    __builtin_amdgcn_s_barrier();
    __builtin_amdgcn_sched_barrier(0);
    if (ks + 2 < ksteps) STAGEK((ks + 2) % 3, ks + 2);
    COMPUTEK(ks % 3);
  }
#undef STAGEK
#undef COMPUTEK
#undef WAITN

  // epilogue: hoist b1/w2 (2 cols per thread), then per-row tproj + gelu + reduce
  float b1v[2], w2v[2];
  #pragma unroll
  for (int j = 0; j < 2; ++j){
    int n = n0 + wcol + j*16 + lo16;
    b1v[j] = b1[n]; w2v[j] = w2[n];
  }
  #pragma unroll
  for (int i = 0; i < 4; ++i)
    #pragma unroll
    for (int reg = 0; reg < 4; ++reg){
      int row = m0 + wrow + i*16 + ((lane >> 4) << 2) + reg;
      int trow = ((row >> 13) << 10) | (row & 1023);
      const float* tp = tproj + (size_t)trow * D768;
      float contrib = 0.f;
      #pragma unroll
      for (int j = 0; j < 2; ++j){
        int n = n0 + wcol + j*16 + lo16;
        float v = acc[i][j][reg] + b1v[j] + tp[n];
        contrib += gelu_f(v) * w2v[j];
      }
      for (int o = 8; o; o >>= 1) contrib += __shfl_xor(contrib, o);
      if (lo16 == 0) atomicAdd(&out[row], contrib);
    }
}

// ---------- 8-wave MFMA GEMM (gate), 128x64 tile, depth-3 ring ----------
__launch_bounds__(512)
__global__ void k_gemm8g(const unsigned short* __restrict__ A, int lda,
                         const unsigned short* __restrict__ Bt, int ldb,
                         int ksteps, int ntn,
                         const float* __restrict__ b1,
                         const float* __restrict__ w2,
                         float* __restrict__ out){
  __shared__ __align__(16) unsigned short As[3][128*32];
  __shared__ __align__(16) unsigned short Bs[3][64*32];
  const int cpx = gridDim.x >> 3;
  const int logical = ((int)blockIdx.x & 7) * cpx + ((int)blockIdx.x >> 3);
  const int m0 = (logical / ntn) * 128, n0 = (logical % ntn) * 64;
  const int t = threadIdx.x, lane = t & 63, w = t >> 6; // 8 waves
  const int wrow = (w >> 2) * 64, wcol = (w & 3) * 16;
  const int lo16 = lane & 15;
  const int hs = ((lane >> 4) ^ ((lo16 >> 1) & 3)) * 8;
  const int crow = lane >> 2;
  const int cseg = (((lane & 3) ^ ((lane >> 3) & 3)) * 8);
  const unsigned short* ga = A  + (size_t)(m0 + w*16 + crow) * lda + cseg;
  const unsigned short* gb = Bt + (size_t)(n0 + w*16 + crow) * ldb + cseg; // valid for w<4
  f32x4 acc[4] = {};

#define STAGEK(BUF, KS) do {                                                   \
    gload16(ga + (size_t)(KS)*32, &As[BUF][w*512]);                            \
    if (w < 4) gload16(gb + (size_t)(KS)*32, &Bs[BUF][w*512]);                 \
  } while (0)

#define COMPUTEK(BUF) do {                                                     \
    const unsigned short* pa_ = &As[BUF][(wrow + lo16)*32 + hs];               \
    const unsigned short* pb_ = &Bs[BUF][(wcol + lo16)*32 + hs];               \
    short8 af_[4], bf_;                                                        \
    _Pragma("unroll")                                                          \
    for (int i = 0; i < 4; ++i) af_[i] = *(const short8*)(pa_ + i*16*32);      \
    bf_ = *(const short8*)pb_;                                                 \
    __builtin_amdgcn_s_setprio(1);                                             \
    _Pragma("unroll")                                                          \
    for (int i = 0; i < 4; ++i)                                                \
      acc[i] = __builtin_amdgcn_mfma_f32_16x16x32_bf16(af_[i], bf_, acc[i], 0, 0, 0); \
    __builtin_amdgcn_s_setprio(0);                                             \
  } while (0)

#define WAITN(n) asm volatile("s_waitcnt vmcnt(" #n ")" ::: "memory")

  {
    int pro = ksteps < 2 ? ksteps : 2;
    for (int p = 0; p < pro; ++p) STAGEK(p, p);
  }
  for (int ks = 0; ks < ksteps; ++ks){
    int rem = ksteps - ks;
    if (rem >= 2){ if (w < 4) WAITN(2); else WAITN(1); }
    else WAITN(0);
    __builtin_amdgcn_s_barrier();
    __builtin_amdgcn_sched_barrier(0);
    if (ks + 2 < ksteps) STAGEK((ks + 2) % 3, ks + 2);
    COMPUTEK(ks % 3);
  }
#undef STAGEK
#undef COMPUTEK
#undef WAITN

  #pragma unroll
  for (int i = 0; i < 4; ++i)
    #pragma unroll
    for (int reg = 0; reg < 4; ++reg){
      int row = m0 + wrow + i*16 + ((lane >> 4) << 2) + reg;
      int n = n0 + wcol + lo16;
      float v = acc[i][reg] + b1[n];
      float contrib = gelu_f(v) * w2[n];
      for (int o = 8; o; o >>= 1) contrib += __shfl_xor(contrib, o);
      if (lo16 == 0) atomicAdd(&out[row], contrib);
    }
}

// ---------- masked softmax over S=8 + weighted summary -> gcat[:,768:1568] (bf16) ----------
__global__ void k_smx(const float* __restrict__ scores, const void* __restrict__ maskp,
                      const int* __restrict__ flag, const unsigned short* __restrict__ sh,
                      const float* __restrict__ feat,
                      unsigned short* __restrict__ gcat){
  int bt = blockIdx.x;
  int b = bt >> 10, tt = bt & 1023;
  int t = threadIdx.x; // 192
  int f = *flag;
  float sc[8], mk[8];
  #pragma unroll
  for (int s = 0; s < 8; ++s){
    size_t idx = ((size_t)(b*8 + s) << 10) + tt;
    bool m = f ? (((const int*)maskp)[idx] != 0)
               : (((const unsigned char*)maskp)[idx] != 0);
    mk[s] = m ? 1.f : 0.f;
    float v = scores[idx];
    sc[s] = m ? v : -10000.f;
  }
  float mx = sc[0];
  #pragma unroll
  for (int s = 1; s < 8; ++s) mx = fmaxf(mx, sc[s]);
  float e[8], sum = 0.f;
  #pragma unroll
  for (int s = 0; s < 8; ++s){ e[s] = __expf(sc[s] - mx); sum += e[s]; }
  float inv = 1.f / sum;
  float wv[8], sum2 = 0.f;
  #pragma unroll
  for (int s = 0; s < 8; ++s){ wv[s] = e[s] * inv * mk[s]; sum2 += wv[s]; }
  float inv2 = 1.f / fmaxf(sum2, 1e-8f);
  #pragma unroll
  for (int s = 0; s < 8; ++s) wv[s] *= inv2;
  float a0=0.f, a1=0.f, a2=0.f, a3=0.f;
  #pragma unroll
  for (int s = 0; s < 8; ++s){
    const unsigned short* p = sh + (((size_t)(b*8+s) << 10) + tt) * D768 + t*4;
    ushort4 u = *(const ushort4*)p;
    float ws = wv[s];
    a0 += ws * bf2f(u.x); a1 += ws * bf2f(u.y); a2 += ws * bf2f(u.z); a3 += ws * bf2f(u.w);
  }
  ushort4 ub; ub.x=f2bf(a0); ub.y=f2bf(a1); ub.z=f2bf(a2); ub.w=f2bf(a3);
  *(ushort4*)(gcat + (size_t)bt * 1568 + 768 + t*4) = ub;
  if (t < 8){
    int c = 1536 + t*4;
    float4 fv = make_float4(0.f, 0.f, 0.f, 0.f);
    if (c < 1552) fv = *(const float4*)(feat + (size_t)bt * 16 + (c - 1536));
    ushort4 uf; uf.x=f2bf(fv.x); uf.y=f2bf(fv.y); uf.z=f2bf(fv.z); uf.w=f2bf(fv.w);
    *(ushort4*)(gcat + (size_t)bt * 1568 + c) = uf;
  }
}

// ---------- gate=sigmoid(gacc); x=(2-g)*th+g*summary; out=LN(x). 1 wave/row ----------
__global__ __launch_bounds__(256)
void k_final(const float* __restrict__ th, const unsigned short* __restrict__ gcat,
             const float* __restrict__ gacc, const float* __restrict__ og,
             const float* __restrict__ ob, float* __restrict__ out,
             float* __restrict__ outg){
  int row = blockIdx.x * 4 + (threadIdx.x >> 6);
  int lane = threadIdx.x & 63;
  float gv = 1.f / (1.f + __expf(-gacc[row]));
  if (lane == 0) outg[row] = gv;
  const float* tr = th + (size_t)row * D768;
  const unsigned short* sr = gcat + (size_t)row * 1568 + 768;
  float x[12];
  float s = 0.f, ss = 0.f;
  #pragma unroll
  for (int k = 0; k < 3; ++k){
    int c = lane*4 + k*256;
    float4 tv = *(const float4*)(tr + c);
    ushort4 su = *(const ushort4*)(sr + c);
    float v0 = (2.f-gv)*tv.x + gv*bf2f(su.x);
    float v1 = (2.f-gv)*tv.y + gv*bf2f(su.y);
    float v2 = (2.f-gv)*tv.z + gv*bf2f(su.z);
    float v3 = (2.f-gv)*tv.w + gv*bf2f(su.w);
    x[k*4+0]=v0; x[k*4+1]=v1; x[k*4+2]=v2; x[k*4+3]=v3;
    s += v0+v1+v2+v3;
    ss += v0*v0+v1*v1+v2*v2+v3*v3;
  }
  #pragma unroll
  for (int o = 32; o; o >>= 1){ s += __shfl_xor(s, o); ss += __shfl_xor(ss, o); }
  float mean = s*(1.f/768.f), var = ss*(1.f/768.f)-mean*mean;
  float rstd = rsqrtf(var + 1e-5f);
  #pragma unroll
  for (int k = 0; k < 3; ++k){
    int c = lane*4 + k*256;
    float4 gvv = *(const float4*)(og + c);
    float4 bvv = *(const float4*)(ob + c);
    float4 ov;
    ov.x = (x[k*4+0]-mean)*rstd*gvv.x + bvv.x;
    ov.y = (x[k*4+1]-mean)*rstd*gvv.y + bvv.y;
    ov.z = (x[k*4+2]-mean)*rstd*gvv.z + bvv.z;
    ov.w = (x[k*4+3]-mean)*rstd*gvv.w + bvv.w;
    *(float4*)(out + (size_t)row * D768 + c) = ov;
  }
}

extern "C" void kernel_launch(void* const* d_in, const int* in_sizes, int n_in,
                              void* d_out, int out_size, void* d_ws, size_t ws_size,
                              hipStream_t stream){
  const float* target = (const float*)d_in[0];
  const float* support= (const float*)d_in[1];
  const void*  maskp  = d_in[2];
  const float* feat   = (const float*)d_in[3];
  const float* t_g = (const float*)d_in[4];
  const float* t_b = (const float*)d_in[5];
  const float* s_g = (const float*)d_in[6];
  const float* s_b = (const float*)d_in[7];
  const float* o_g = (const float*)d_in[8];
  const float* o_b = (const float*)d_in[9];
  const float* sw1 = (const float*)d_in[10];
  const float* sb1 = (const float*)d_in[11];
  const float* sw2 = (const float*)d_in[12];
  const float* sb2 = (const float*)d_in[13];
  const float* gw1 = (const float*)d_in[14];
  const float* gb1 = (const float*)d_in[15];
  const float* gw2 = (const float*)d_in[16];
  const float* gb2 = (const float*)d_in[17];

  char* wsb = (char*)d_ws;
  size_t off = 0;
  auto alloc = [&](size_t bytes)->void*{
    void* p = wsb + off; off += (bytes + 255) & ~(size_t)255; return p;
  };
  float* th            = (float*)alloc(4096ull*768*4);
  unsigned short* sh   = (unsigned short*)alloc(32768ull*768*2);
  float* tproj         = (float*)alloc(4096ull*768*4);
  unsigned short* gcat = (unsigned short*)alloc(4096ull*1568*2);
  unsigned short* WtA  = (unsigned short*)alloc(768ull*768*2);
  unsigned short* WtB  = (unsigned short*)alloc(768ull*768*2);
  unsigned short* WtG  = (unsigned short*)alloc(768ull*1568*2);
  float* scores        = (float*)alloc(32768ull*4);
  float* gacc          = (float*)alloc(4096ull*4);
  int*   flag          = (int*)alloc(256);

  float* outm = (float*)d_out;       // (B,T,D)
  float* outg = outm + 4096ull*768;  // (B,T)

  // init + maskdet + weight transposes + target LN + support LN (one launch)
  k_mega<<<11672, 256, 0, stream>>>(target, support, t_g, t_b, s_g, s_b,
                                    th, gcat, sh, sw1, gw1, WtA, WtB, WtG,
                                    scores, sb2, gacc, gb2,
                                    (const unsigned char*)maskp, flag);
  // tproj = th @ W1a   (384 blocks, ntn=12)
  k_gemm<0,64><<<384, 256, 0, stream>>>(gcat, 1568, WtA, 768, 24, 12,
                                        nullptr, nullptr, nullptr, tproj);
  // scores += rowsum(gelu(sh@W1b + tproj + b1) * w2)   (8-wave, 1536 blocks, ntn=6)
  k_gemm8<<<1536, 512, 0, stream>>>(sh, 768, WtB, 768, 24, 6,
                                    tproj, sb1, sw2, scores);
  // masked softmax + summary -> gcat[:, 768:1568]
  k_smx<<<4096, 192, 0, stream>>>(scores, maskp, flag, sh, feat, gcat);
  // gate_acc += rowsum(gelu(gcat@gW1 + gb1) * gw2)   (8-wave, 384 blocks, ntn=12)
  k_gemm8g<<<384, 512, 0, stream>>>(gcat, 1568, WtG, 1568, 49, 12,
                                    gb1, gw2, gacc);
  k_final<<<1024, 256, 0, stream>>>(th, gcat, gacc, o_g, o_b, outm, outg);
}

// Round 16
// 170.611 us; speedup vs baseline: 1.0590x; 1.0112x over previous
//
#include <hip/hip_runtime.h>
#include <hip/hip_bf16.h>

#define D768 768

typedef __attribute__((ext_vector_type(8))) short short8;
typedef __attribute__((ext_vector_type(4))) float f32x4;

__device__ __forceinline__ unsigned short f2bf(float f){
  union { float f; unsigned u; } v; v.f = f;
  unsigned r = v.u + 0x7FFFu + ((v.u >> 16) & 1u);
  return (unsigned short)(r >> 16);
}
__device__ __forceinline__ float bf2f(unsigned short u){
  union { unsigned u; float f; } v; v.u = ((unsigned)u) << 16;
  return v.f;
}
// exact-erf GELU via Abramowitz-Stegun 7.1.26 (|eps| <= 1.5e-7), ~13 VALU + exp + rcp
__device__ __forceinline__ float gelu_f(float x){
  float y = fabsf(x) * 0.7071067811865475f;
  float t = __builtin_amdgcn_rcpf(fmaf(0.3275911f, y, 1.0f));
  float p = fmaf(fmaf(fmaf(fmaf(1.061405429f, t, -1.453152027f), t, 1.421413741f),
                      t, -0.284496736f), t, 0.254829592f) * t;
  float e = __expf(-y * y);
  float erf_abs = fmaf(-p, e, 1.0f);
  float erfv = copysignf(erf_abs, x);
  return 0.5f * x * (1.0f + erfv);
}
__device__ __forceinline__ void gload16(const void* g, void* l){
  __builtin_amdgcn_global_load_lds((const __attribute__((address_space(1))) void*)g,
                                   (__attribute__((address_space(3))) void*)l, 16, 0, 0);
}

// ---------- MEGA kernel: init (0..127) + weight transpose (128..2455) +
// target LN (2456..3479, 4 rows/block) + support LN (3480..11671, 4 rows/block).
__global__ __launch_bounds__(256)
void k_mega(const float* __restrict__ target, const float* __restrict__ support,
            const float* __restrict__ t_g, const float* __restrict__ t_b,
            const float* __restrict__ s_g, const float* __restrict__ s_b,
            float* __restrict__ th, unsigned short* __restrict__ gcat,
            unsigned short* __restrict__ sh,
            const float* __restrict__ sw1, const float* __restrict__ gw1,
            unsigned short* __restrict__ WtA, unsigned short* __restrict__ WtB,
            unsigned short* __restrict__ WtG,
            float* __restrict__ scores, const float* __restrict__ sb2,
            float* __restrict__ gacc, const float* __restrict__ gb2,
            const unsigned char* __restrict__ m, int* __restrict__ flag){
  int blk = blockIdx.x;
  int t = threadIdx.x;
  if (blk < 128){
    int i = blk * 256 + t;
    if (i < 32768) scores[i] = sb2[0];
    if (i < 4096)  gacc[i]   = gb2[0];
    if (blk == 0){
      __shared__ int s;
      if (t == 0) s = 0;
      __syncthreads();
      int nz = 0;
      for (int j = t; j < 2048; j += 256) nz += (m[4*j+1] != 0);
      atomicAdd(&s, nz);
      __syncthreads();
      if (t == 0) *flag = (s == 0) ? 1 : 0; // 1 => 4-byte mask elems
    }
    return;
  }
  if (blk < 2456){
    int tile = blk - 128;
    const float* W; unsigned short* Wt; int Kin, Kpad;
    if (tile < 576)      { W = sw1;              Wt = WtA; Kin = 768;  Kpad = 768;  }
    else if (tile < 1152){ W = sw1 + 768ull*768; Wt = WtB; Kin = 768;  Kpad = 768;  tile -= 576; }
    else                 { W = gw1;              Wt = WtG; Kin = 1552; Kpad = 1568; tile -= 1152; }
    int ntk = Kpad >> 5;
    int k0 = (tile % ntk) << 5, n0 = (tile / ntk) << 5;
    __shared__ float ts[32][33];
    int tx = t & 31, ty = t >> 5; // 32x8
    #pragma unroll
    for (int r = 0; r < 4; ++r){
      int k = k0 + ty + r*8;
      ts[ty + r*8][tx] = (k < Kin) ? W[(size_t)k * D768 + n0 + tx] : 0.f;
    }
    __syncthreads();
    #pragma unroll
    for (int r = 0; r < 4; ++r){
      int n = n0 + ty + r*8;
      Wt[(size_t)n * Kpad + k0 + tx] = f2bf(ts[tx][ty + r*8]);
    }
    return;
  }
  // LayerNorm: 1 wave per row, 4 rows per block
  bool isT = blk < 3480;
  int row = (isT ? (blk - 2456) : (blk - 3480)) * 4 + (t >> 6);
  int lane = t & 63;
  const float* xr = (isT ? target : support) + (size_t)row * D768;
  float4 v0 = *(const float4*)(xr + lane*4);
  float4 v1 = *(const float4*)(xr + 256 + lane*4);
  float4 v2 = *(const float4*)(xr + 512 + lane*4);
  float s  = v0.x+v0.y+v0.z+v0.w + v1.x+v1.y+v1.z+v1.w + v2.x+v2.y+v2.z+v2.w;
  float ss = v0.x*v0.x+v0.y*v0.y+v0.z*v0.z+v0.w*v0.w
           + v1.x*v1.x+v1.y*v1.y+v1.z*v1.z+v1.w*v1.w
           + v2.x*v2.x+v2.y*v2.y+v2.z*v2.z+v2.w*v2.w;
  #pragma unroll
  for (int o = 32; o; o >>= 1){ s += __shfl_xor(s, o); ss += __shfl_xor(ss, o); }
  float mean = s * (1.f/768.f);
  float var  = ss * (1.f/768.f) - mean*mean;
  float rstd = rsqrtf(var + 1e-5f);
  const float* gg = isT ? t_g : s_g;
  const float* bb = isT ? t_b : s_b;
  #pragma unroll
  for (int k = 0; k < 3; ++k){
    int c = lane*4 + k*256;
    float4 v = (k==0) ? v0 : (k==1) ? v1 : v2;
    float4 gv = *(const float4*)(gg + c);
    float4 bv = *(const float4*)(bb + c);
    float o0 = (v.x-mean)*rstd*gv.x + bv.x;
    float o1 = (v.y-mean)*rstd*gv.y + bv.y;
    float o2 = (v.z-mean)*rstd*gv.z + bv.z;
    float o3 = (v.w-mean)*rstd*gv.w + bv.w;
    ushort4 ub; ub.x=f2bf(o0); ub.y=f2bf(o1); ub.z=f2bf(o2); ub.w=f2bf(o3);
    if (isT){
      float4 ov; ov.x=o0; ov.y=o1; ov.z=o2; ov.w=o3;
      *(float4*)(th + (size_t)row * D768 + c) = ov;
      *(ushort4*)(gcat + (size_t)row * 1568 + c) = ub;
    } else {
      *(ushort4*)(sh + (size_t)row * D768 + c) = ub;
    }
  }
}

// ---------- 4-wave MFMA GEMM (tproj), 128xBN tile, depth-3 ring ----------
template<int MODE, int BN>
__launch_bounds__(256)
__global__ void k_gemm(const unsigned short* __restrict__ A, int lda,
                       const unsigned short* __restrict__ Bt, int ldb,
                       int ksteps, int ntn,
                       const float* __restrict__ tproj,
                       const float* __restrict__ b1,
                       const float* __restrict__ w2,
                       float* __restrict__ out){
  constexpr int NJ  = BN / 32;
  constexpr int BCH = BN / 64;
  __shared__ __align__(16) unsigned short As[3][128*32];
  __shared__ __align__(16) unsigned short Bs[3][BN*32];
  const int cpx = gridDim.x >> 3;
  const int logical = ((int)blockIdx.x & 7) * cpx + ((int)blockIdx.x >> 3);
  const int m0 = (logical / ntn) * 128, n0 = (logical % ntn) * BN;
  const int t = threadIdx.x, lane = t & 63, w = t >> 6;
  const int wrow = (w >> 1) * 64, wcol = (w & 1) * (BN/2);
  const int lo16 = lane & 15;
  const int hs = ((lane >> 4) ^ ((lo16 >> 1) & 3)) * 8;
  const int crow = lane >> 2;
  const int cseg = (((lane & 3) ^ ((lane >> 3) & 3)) * 8);
  const unsigned short* ga = A  + (size_t)(m0 + w*32 + crow) * lda + cseg;
  const unsigned short* gb = Bt + (size_t)(n0 + w*(BN/4) + crow) * ldb + cseg;
  f32x4 acc[4][NJ] = {};

#define STAGEK(BUF, KS) do {                                                   \
    const unsigned short* gak_ = ga + (size_t)(KS)*32;                         \
    const unsigned short* gbk_ = gb + (size_t)(KS)*32;                         \
    _Pragma("unroll")                                                          \
    for (int c = 0; c < 2; ++c)                                                \
      gload16(gak_ + (size_t)(c*16)*lda, &As[BUF][w*1024 + c*512]);            \
    _Pragma("unroll")                                                          \
    for (int c = 0; c < BCH; ++c)                                              \
      gload16(gbk_ + (size_t)(c*16)*ldb, &Bs[BUF][w*(BN/4)*32 + c*512]);       \
  } while (0)

#define COMPUTEK(BUF) do {                                                     \
    const unsigned short* pa_ = &As[BUF][(wrow + lo16)*32 + hs];               \
    const unsigned short* pb_ = &Bs[BUF][(wcol + lo16)*32 + hs];               \
    short8 af_[4], bf_[NJ];                                                    \
    _Pragma("unroll")                                                          \
    for (int i = 0; i < 4; ++i) af_[i] = *(const short8*)(pa_ + i*16*32);      \
    _Pragma("unroll")                                                          \
    for (int j = 0; j < NJ; ++j) bf_[j] = *(const short8*)(pb_ + j*16*32);     \
    __builtin_amdgcn_s_setprio(1);                                             \
    _Pragma("unroll")                                                          \
    for (int i = 0; i < 4; ++i)                                                \
      _Pragma("unroll")                                                        \
      for (int j = 0; j < NJ; ++j)                                             \
        acc[i][j] = __builtin_amdgcn_mfma_f32_16x16x32_bf16(af_[i], bf_[j], acc[i][j], 0, 0, 0); \
    __builtin_amdgcn_s_setprio(0);                                             \
  } while (0)

#define WAITN(n) asm volatile("s_waitcnt vmcnt(" #n ")" ::: "memory")

  {
    int pro = ksteps < 2 ? ksteps : 2;
    for (int p = 0; p < pro; ++p) STAGEK(p, p);
  }
  for (int ks = 0; ks < ksteps; ++ks){
    int rem = ksteps - ks;
    if (rem >= 2){ if constexpr (BCH == 2) WAITN(4); else WAITN(3); }
    else WAITN(0);
    __builtin_amdgcn_s_barrier();
    __builtin_amdgcn_sched_barrier(0);
    if (ks + 2 < ksteps) STAGEK((ks + 2) % 3, ks + 2);
    COMPUTEK(ks % 3);
  }
#undef STAGEK
#undef COMPUTEK
#undef WAITN

  if (MODE == 0){
    #pragma unroll
    for (int i = 0; i < 4; ++i)
      #pragma unroll
      for (int reg = 0; reg < 4; ++reg){
        int row = m0 + wrow + i*16 + ((lane >> 4) << 2) + reg;
        float* orow = out + (size_t)row * D768 + n0 + wcol + (lane & 15);
        #pragma unroll
        for (int j = 0; j < NJ; ++j) orow[j*16] = acc[i][j][reg];
      }
  } else {
    #pragma unroll
    for (int i = 0; i < 4; ++i)
      #pragma unroll
      for (int reg = 0; reg < 4; ++reg){
        int row = m0 + wrow + i*16 + ((lane >> 4) << 2) + reg;
        const float* tp = nullptr;
        if (MODE == 1){
          int trow = ((row >> 13) << 10) | (row & 1023);
          tp = tproj + (size_t)trow * D768;
        }
        float contrib = 0.f;
        #pragma unroll
        for (int j = 0; j < NJ; ++j){
          int n = n0 + wcol + j*16 + (lane & 15);
          float v = acc[i][j][reg] + b1[n];
          if (MODE == 1) v += tp[n];
          contrib += gelu_f(v) * w2[n];
        }
        for (int o = 8; o; o >>= 1) contrib += __shfl_xor(contrib, o);
        if ((lane & 15) == 0) atomicAdd(&out[row], contrib);
      }
  }
}

// ---------- 8-wave MFMA GEMM (score), 256x128 tile, depth-3 ring ----------
// Wave grid 4M x 2N: each wave 64x64 (4x4 frags) -> 8 ds_reads per 16 MFMA
// (0.5 reads/MFMA vs 0.75 at 64x32) — attacks the shared LDS-read pipe, the
// diagnosed binder (two schedules at 30%/59% occupancy gave identical time).
// LDS 3x24KB=72KB -> 2 blocks/CU. Stage: 2 A-chunks + 1 B-chunk per wave (L=3).
// Ring/barrier/WAR proofs and both-sides segment swizzle identical.
__launch_bounds__(512)
__global__ void k_gemm8(const unsigned short* __restrict__ A, int lda,
                        const unsigned short* __restrict__ Bt, int ldb,
                        int ksteps, int ntn,
                        const float* __restrict__ tproj,
                        const float* __restrict__ b1,
                        const float* __restrict__ w2,
                        float* __restrict__ out){
  __shared__ __align__(16) unsigned short As[3][256*32];
  __shared__ __align__(16) unsigned short Bs[3][128*32];
  const int cpx = gridDim.x >> 3;
  const int logical = ((int)blockIdx.x & 7) * cpx + ((int)blockIdx.x >> 3);
  const int m0 = (logical / ntn) * 256, n0 = (logical % ntn) * 128;
  const int t = threadIdx.x, lane = t & 63, w = t >> 6; // 8 waves, 4M x 2N
  const int wrow = (w >> 1) * 64, wcol = (w & 1) * 64;
  const int lo16 = lane & 15;
  const int hs = ((lane >> 4) ^ ((lo16 >> 1) & 3)) * 8;
  const int crow = lane >> 2;
  const int cseg = (((lane & 3) ^ ((lane >> 3) & 3)) * 8);
  const unsigned short* ga = A  + (size_t)(m0 + w*32 + crow) * lda + cseg;
  const unsigned short* gb = Bt + (size_t)(n0 + w*16 + crow) * ldb + cseg;
  f32x4 acc[4][4] = {};

#define STAGEK(BUF, KS) do {                                                   \
    const unsigned short* gak_ = ga + (size_t)(KS)*32;                         \
    gload16(gak_,                    &As[BUF][w*1024]);                        \
    gload16(gak_ + (size_t)16*lda,   &As[BUF][w*1024 + 512]);                  \
    gload16(gb + (size_t)(KS)*32,    &Bs[BUF][w*512]);                         \
  } while (0)

#define COMPUTEK(BUF) do {                                                     \
    const unsigned short* pa_ = &As[BUF][(wrow + lo16)*32 + hs];               \
    const unsigned short* pb_ = &Bs[BUF][(wcol + lo16)*32 + hs];               \
    short8 af_[4], bf_[4];                                                     \
    _Pragma("unroll")                                                          \
    for (int i = 0; i < 4; ++i) af_[i] = *(const short8*)(pa_ + i*16*32);      \
    _Pragma("unroll")                                                          \
    for (int j = 0; j < 4; ++j) bf_[j] = *(const short8*)(pb_ + j*16*32);      \
    __builtin_amdgcn_s_setprio(1);                                             \
    _Pragma("unroll")                                                          \
    for (int i = 0; i < 4; ++i)                                                \
      _Pragma("unroll")                                                        \
      for (int j = 0; j < 4; ++j)                                              \
        acc[i][j] = __builtin_amdgcn_mfma_f32_16x16x32_bf16(af_[i], bf_[j], acc[i][j], 0, 0, 0); \
    __builtin_amdgcn_s_setprio(0);                                             \
  } while (0)

#define WAITN(n) asm volatile("s_waitcnt vmcnt(" #n ")" ::: "memory")

  {
    int pro = ksteps < 2 ? ksteps : 2;
    for (int p = 0; p < pro; ++p) STAGEK(p, p);
  }
  for (int ks = 0; ks < ksteps; ++ks){
    int rem = ksteps - ks;
    if (rem >= 2) WAITN(3);
    else WAITN(0);
    __builtin_amdgcn_s_barrier();
    __builtin_amdgcn_sched_barrier(0);
    if (ks + 2 < ksteps) STAGEK((ks + 2) % 3, ks + 2);
    COMPUTEK(ks % 3);
  }
#undef STAGEK
#undef COMPUTEK
#undef WAITN

  // epilogue: hoist b1/w2 (4 cols per thread), then per-row tproj + gelu + reduce
  float b1v[4], w2v[4];
  #pragma unroll
  for (int j = 0; j < 4; ++j){
    int n = n0 + wcol + j*16 + lo16;
    b1v[j] = b1[n]; w2v[j] = w2[n];
  }
  #pragma unroll
  for (int i = 0; i < 4; ++i)
    #pragma unroll
    for (int reg = 0; reg < 4; ++reg){
      int row = m0 + wrow + i*16 + ((lane >> 4) << 2) + reg;
      int trow = ((row >> 13) << 10) | (row & 1023);
      const float* tp = tproj + (size_t)trow * D768;
      float contrib = 0.f;
      #pragma unroll
      for (int j = 0; j < 4; ++j){
        int n = n0 + wcol + j*16 + lo16;
        float v = acc[i][j][reg] + b1v[j] + tp[n];
        contrib += gelu_f(v) * w2v[j];
      }
      for (int o = 8; o; o >>= 1) contrib += __shfl_xor(contrib, o);
      if (lo16 == 0) atomicAdd(&out[row], contrib);
    }
}

// ---------- 8-wave MFMA GEMM (gate), 128x64 tile, depth-3 ring ----------
__launch_bounds__(512)
__global__ void k_gemm8g(const unsigned short* __restrict__ A, int lda,
                         const unsigned short* __restrict__ Bt, int ldb,
                         int ksteps, int ntn,
                         const float* __restrict__ b1,
                         const float* __restrict__ w2,
                         float* __restrict__ out){
  __shared__ __align__(16) unsigned short As[3][128*32];
  __shared__ __align__(16) unsigned short Bs[3][64*32];
  const int cpx = gridDim.x >> 3;
  const int logical = ((int)blockIdx.x & 7) * cpx + ((int)blockIdx.x >> 3);
  const int m0 = (logical / ntn) * 128, n0 = (logical % ntn) * 64;
  const int t = threadIdx.x, lane = t & 63, w = t >> 6; // 8 waves
  const int wrow = (w >> 2) * 64, wcol = (w & 3) * 16;
  const int lo16 = lane & 15;
  const int hs = ((lane >> 4) ^ ((lo16 >> 1) & 3)) * 8;
  const int crow = lane >> 2;
  const int cseg = (((lane & 3) ^ ((lane >> 3) & 3)) * 8);
  const unsigned short* ga = A  + (size_t)(m0 + w*16 + crow) * lda + cseg;
  const unsigned short* gb = Bt + (size_t)(n0 + w*16 + crow) * ldb + cseg; // valid for w<4
  f32x4 acc[4] = {};

#define STAGEK(BUF, KS) do {                                                   \
    gload16(ga + (size_t)(KS)*32, &As[BUF][w*512]);                            \
    if (w < 4) gload16(gb + (size_t)(KS)*32, &Bs[BUF][w*512]);                 \
  } while (0)

#define COMPUTEK(BUF) do {                                                     \
    const unsigned short* pa_ = &As[BUF][(wrow + lo16)*32 + hs];               \
    const unsigned short* pb_ = &Bs[BUF][(wcol + lo16)*32 + hs];               \
    short8 af_[4], bf_;                                                        \
    _Pragma("unroll")                                                          \
    for (int i = 0; i < 4; ++i) af_[i] = *(const short8*)(pa_ + i*16*32);      \
    bf_ = *(const short8*)pb_;                                                 \
    __builtin_amdgcn_s_setprio(1);                                             \
    _Pragma("unroll")                                                          \
    for (int i = 0; i < 4; ++i)                                                \
      acc[i] = __builtin_amdgcn_mfma_f32_16x16x32_bf16(af_[i], bf_, acc[i], 0, 0, 0); \
    __builtin_amdgcn_s_setprio(0);                                             \
  } while (0)

#define WAITN(n) asm volatile("s_waitcnt vmcnt(" #n ")" ::: "memory")

  {
    int pro = ksteps < 2 ? ksteps : 2;
    for (int p = 0; p < pro; ++p) STAGEK(p, p);
  }
  for (int ks = 0; ks < ksteps; ++ks){
    int rem = ksteps - ks;
    if (rem >= 2){ if (w < 4) WAITN(2); else WAITN(1); }
    else WAITN(0);
    __builtin_amdgcn_s_barrier();
    __builtin_amdgcn_sched_barrier(0);
    if (ks + 2 < ksteps) STAGEK((ks + 2) % 3, ks + 2);
    COMPUTEK(ks % 3);
  }
#undef STAGEK
#undef COMPUTEK
#undef WAITN

  #pragma unroll
  for (int i = 0; i < 4; ++i)
    #pragma unroll
    for (int reg = 0; reg < 4; ++reg){
      int row = m0 + wrow + i*16 + ((lane >> 4) << 2) + reg;
      int n = n0 + wcol + lo16;
      float v = acc[i][reg] + b1[n];
      float contrib = gelu_f(v) * w2[n];
      for (int o = 8; o; o >>= 1) contrib += __shfl_xor(contrib, o);
      if (lo16 == 0) atomicAdd(&out[row], contrib);
    }
}

// ---------- masked softmax over S=8 + weighted summary -> gcat[:,768:1568] (bf16) ----------
__global__ void k_smx(const float* __restrict__ scores, const void* __restrict__ maskp,
                      const int* __restrict__ flag, const unsigned short* __restrict__ sh,
                      const float* __restrict__ feat,
                      unsigned short* __restrict__ gcat){
  int bt = blockIdx.x;
  int b = bt >> 10, tt = bt & 1023;
  int t = threadIdx.x; // 192
  int f = *flag;
  float sc[8], mk[8];
  #pragma unroll
  for (int s = 0; s < 8; ++s){
    size_t idx = ((size_t)(b*8 + s) << 10) + tt;
    bool m = f ? (((const int*)maskp)[idx] != 0)
               : (((const unsigned char*)maskp)[idx] != 0);
    mk[s] = m ? 1.f : 0.f;
    float v = scores[idx];
    sc[s] = m ? v : -10000.f;
  }
  float mx = sc[0];
  #pragma unroll
  for (int s = 1; s < 8; ++s) mx = fmaxf(mx, sc[s]);
  float e[8], sum = 0.f;
  #pragma unroll
  for (int s = 0; s < 8; ++s){ e[s] = __expf(sc[s] - mx); sum += e[s]; }
  float inv = 1.f / sum;
  float wv[8], sum2 = 0.f;
  #pragma unroll
  for (int s = 0; s < 8; ++s){ wv[s] = e[s] * inv * mk[s]; sum2 += wv[s]; }
  float inv2 = 1.f / fmaxf(sum2, 1e-8f);
  #pragma unroll
  for (int s = 0; s < 8; ++s) wv[s] *= inv2;
  float a0=0.f, a1=0.f, a2=0.f, a3=0.f;
  #pragma unroll
  for (int s = 0; s < 8; ++s){
    const unsigned short* p = sh + (((size_t)(b*8+s) << 10) + tt) * D768 + t*4;
    ushort4 u = *(const ushort4*)p;
    float ws = wv[s];
    a0 += ws * bf2f(u.x); a1 += ws * bf2f(u.y); a2 += ws * bf2f(u.z); a3 += ws * bf2f(u.w);
  }
  ushort4 ub; ub.x=f2bf(a0); ub.y=f2bf(a1); ub.z=f2bf(a2); ub.w=f2bf(a3);
  *(ushort4*)(gcat + (size_t)bt * 1568 + 768 + t*4) = ub;
  if (t < 8){
    int c = 1536 + t*4;
    float4 fv = make_float4(0.f, 0.f, 0.f, 0.f);
    if (c < 1552) fv = *(const float4*)(feat + (size_t)bt * 16 + (c - 1536));
    ushort4 uf; uf.x=f2bf(fv.x); uf.y=f2bf(fv.y); uf.z=f2bf(fv.z); uf.w=f2bf(fv.w);
    *(ushort4*)(gcat + (size_t)bt * 1568 + c) = uf;
  }
}

// ---------- gate=sigmoid(gacc); x=(2-g)*th+g*summary; out=LN(x). 1 wave/row ----------
__global__ __launch_bounds__(256)
void k_final(const float* __restrict__ th, const unsigned short* __restrict__ gcat,
             const float* __restrict__ gacc, const float* __restrict__ og,
             const float* __restrict__ ob, float* __restrict__ out,
             float* __restrict__ outg){
  int row = blockIdx.x * 4 + (threadIdx.x >> 6);
  int lane = threadIdx.x & 63;
  float gv = 1.f / (1.f + __expf(-gacc[row]));
  if (lane == 0) outg[row] = gv;
  const float* tr = th + (size_t)row * D768;
  const unsigned short* sr = gcat + (size_t)row * 1568 + 768;
  float x[12];
  float s = 0.f, ss = 0.f;
  #pragma unroll
  for (int k = 0; k < 3; ++k){
    int c = lane*4 + k*256;
    float4 tv = *(const float4*)(tr + c);
    ushort4 su = *(const ushort4*)(sr + c);
    float v0 = (2.f-gv)*tv.x + gv*bf2f(su.x);
    float v1 = (2.f-gv)*tv.y + gv*bf2f(su.y);
    float v2 = (2.f-gv)*tv.z + gv*bf2f(su.z);
    float v3 = (2.f-gv)*tv.w + gv*bf2f(su.w);
    x[k*4+0]=v0; x[k*4+1]=v1; x[k*4+2]=v2; x[k*4+3]=v3;
    s += v0+v1+v2+v3;
    ss += v0*v0+v1*v1+v2*v2+v3*v3;
  }
  #pragma unroll
  for (int o = 32; o; o >>= 1){ s += __shfl_xor(s, o); ss += __shfl_xor(ss, o); }
  float mean = s*(1.f/768.f), var = ss*(1.f/768.f)-mean*mean;
  float rstd = rsqrtf(var + 1e-5f);
  #pragma unroll
  for (int k = 0; k < 3; ++k){
    int c = lane*4 + k*256;
    float4 gvv = *(const float4*)(og + c);
    float4 bvv = *(const float4*)(ob + c);
    float4 ov;
    ov.x = (x[k*4+0]-mean)*rstd*gvv.x + bvv.x;
    ov.y = (x[k*4+1]-mean)*rstd*gvv.y + bvv.y;
    ov.z = (x[k*4+2]-mean)*rstd*gvv.z + bvv.z;
    ov.w = (x[k*4+3]-mean)*rstd*gvv.w + bvv.w;
    *(float4*)(out + (size_t)row * D768 + c) = ov;
  }
}

extern "C" void kernel_launch(void* const* d_in, const int* in_sizes, int n_in,
                              void* d_out, int out_size, void* d_ws, size_t ws_size,
                              hipStream_t stream){
  const float* target = (const float*)d_in[0];
  const float* support= (const float*)d_in[1];
  const void*  maskp  = d_in[2];
  const float* feat   = (const float*)d_in[3];
  const float* t_g = (const float*)d_in[4];
  const float* t_b = (const float*)d_in[5];
  const float* s_g = (const float*)d_in[6];
  const float* s_b = (const float*)d_in[7];
  const float* o_g = (const float*)d_in[8];
  const float* o_b = (const float*)d_in[9];
  const float* sw1 = (const float*)d_in[10];
  const float* sb1 = (const float*)d_in[11];
  const float* sw2 = (const float*)d_in[12];
  const float* sb2 = (const float*)d_in[13];
  const float* gw1 = (const float*)d_in[14];
  const float* gb1 = (const float*)d_in[15];
  const float* gw2 = (const float*)d_in[16];
  const float* gb2 = (const float*)d_in[17];

  char* wsb = (char*)d_ws;
  size_t off = 0;
  auto alloc = [&](size_t bytes)->void*{
    void* p = wsb + off; off += (bytes + 255) & ~(size_t)255; return p;
  };
  float* th            = (float*)alloc(4096ull*768*4);
  unsigned short* sh   = (unsigned short*)alloc(32768ull*768*2);
  float* tproj         = (float*)alloc(4096ull*768*4);
  unsigned short* gcat = (unsigned short*)alloc(4096ull*1568*2);
  unsigned short* WtA  = (unsigned short*)alloc(768ull*768*2);
  unsigned short* WtB  = (unsigned short*)alloc(768ull*768*2);
  unsigned short* WtG  = (unsigned short*)alloc(768ull*1568*2);
  float* scores        = (float*)alloc(32768ull*4);
  float* gacc          = (float*)alloc(4096ull*4);
  int*   flag          = (int*)alloc(256);

  float* outm = (float*)d_out;       // (B,T,D)
  float* outg = outm + 4096ull*768;  // (B,T)

  // init + maskdet + weight transposes + target LN + support LN (one launch)
  k_mega<<<11672, 256, 0, stream>>>(target, support, t_g, t_b, s_g, s_b,
                                    th, gcat, sh, sw1, gw1, WtA, WtB, WtG,
                                    scores, sb2, gacc, gb2,
                                    (const unsigned char*)maskp, flag);
  // tproj = th @ W1a   (384 blocks, ntn=12)
  k_gemm<0,64><<<384, 256, 0, stream>>>(gcat, 1568, WtA, 768, 24, 12,
                                        nullptr, nullptr, nullptr, tproj);
  // scores += rowsum(gelu(sh@W1b + tproj + b1) * w2)   (256x128 tile, 768 blocks, ntn=6)
  k_gemm8<<<768, 512, 0, stream>>>(sh, 768, WtB, 768, 24, 6,
                                   tproj, sb1, sw2, scores);
  // masked softmax + summary -> gcat[:, 768:1568]
  k_smx<<<4096, 192, 0, stream>>>(scores, maskp, flag, sh, feat, gcat);
  // gate_acc += rowsum(gelu(gcat@gW1 + gb1) * gw2)   (8-wave, 384 blocks, ntn=12)
  k_gemm8g<<<384, 512, 0, stream>>>(gcat, 1568, WtG, 1568, 49, 12,
                                    gb1, gw2, gacc);
  k_final<<<1024, 256, 0, stream>>>(th, gcat, gacc, o_g, o_b, outm, outg);
}